// Round 2
// baseline (2606.669 us; speedup 1.0000x reference)
//
#include <hip/hip_runtime.h>
#include <cstdint>
#include <cstddef>

#define GDIM 512

typedef __attribute__((ext_vector_type(8))) short short8;
typedef __attribute__((ext_vector_type(4))) float f32x4;

__device__ __forceinline__ short f2bf(float f) {
  unsigned u = __float_as_uint(f);
  u = u + 0x7fffu + ((u >> 16) & 1u);  // round-to-nearest-even
  return (short)(u >> 16);
}

// ---------------------------------------------------------------- hash table
__device__ __forceinline__ int hash_lookup(int key, const int* __restrict__ keys,
                                           const int* __restrict__ vals, unsigned capmask) {
  unsigned slot = ((unsigned)key * 2654435761u) & capmask;
  while (true) {
    int kk = keys[slot];
    if (kk == key) return vals[slot];
    if (kk == -1) return -1;
    slot = (slot + 1) & capmask;
  }
}

__global__ void k_build_table(const int* __restrict__ coords, int n, int sh, int Gs,
                              int* __restrict__ keys, int* __restrict__ vals, unsigned capmask) {
  int i = blockIdx.x * blockDim.x + threadIdx.x;
  if (i >= n) return;
  int b = coords[4 * i];
  int key = ((b * Gs + (coords[4 * i + 1] >> sh)) * Gs + (coords[4 * i + 2] >> sh)) * Gs +
            (coords[4 * i + 3] >> sh);
  unsigned slot = ((unsigned)key * 2654435761u) & capmask;
  while (true) {
    int prev = atomicCAS(&keys[slot], -1, key);
    if (prev == -1) { vals[slot] = i; return; }
    slot = (slot + 1) & capmask;
  }
}

// ---------------------------------------------- conv: idxT (transposed query)
// grid (cdiv(m,256), 27); coalesced int4 coord reads, coalesced idxT writes.
__global__ void k_query_idx_t(const int* __restrict__ oc, int m, int sh, int Gs,
                              const int* __restrict__ keys, const int* __restrict__ vals,
                              unsigned capmask, int* __restrict__ idxT) {
  int k = blockIdx.y;
  int o = blockIdx.x * blockDim.x + threadIdx.x;
  if (o >= m) return;
  int stride = 1 << sh;
  int dx = k / 9 - 1, dy = (k / 3) % 3 - 1, dz = k % 3 - 1;
  int4 c = *(const int4*)(oc + 4 * o);
  int qx = c.y + dx * stride;
  int qy = c.z + dy * stride;
  int qz = c.w + dz * stride;
  int res = -1;
  if ((unsigned)qx < GDIM && (unsigned)qy < GDIM && (unsigned)qz < GDIM) {
    int key = ((c.x * Gs + (qx >> sh)) * Gs + (qy >> sh)) * Gs + (qz >> sh);
    res = hash_lookup(key, keys, vals, capmask);
  }
  idxT[(size_t)k * m + o] = res;
}

// Split pairs into owner (first hit per output; exactly one per output) and
// rest. Every output is guaranteed >=1 hit (its generating child cell is in
// the query range), so owner GEMM can plain-store (no memset, no atomics).
// Wave-aggregated count atomics.
__global__ void k_make_pairs(const int* __restrict__ idxT, int m,
                             int* __restrict__ po_o, int* __restrict__ pi_o,
                             int* __restrict__ po_r, int* __restrict__ pi_r,
                             int* __restrict__ cnts, int mcap) {
  int o = blockIdx.x * blockDim.x + threadIdx.x;
  bool act = o < m;
  int lane = threadIdx.x & 63;
  bool owned = false;
  for (int k = 0; k < 27; ++k) {
    int i = act ? idxT[(size_t)k * m + o] : -1;
    bool hit = i >= 0;
    bool isown = hit && !owned;
    if (isown) owned = true;
    bool isrest = hit && !isown;
    unsigned long long bo = __ballot(isown);
    if (bo) {
      int ldr = __ffsll((unsigned long long)bo) - 1;
      int base = 0;
      if (lane == ldr) base = atomicAdd(&cnts[k], __popcll(bo));
      base = __shfl(base, ldr);
      if (isown) {
        int p = base + __popcll(bo & ((1ull << lane) - 1ull));
        po_o[k * mcap + p] = o;
        pi_o[k * mcap + p] = i;
      }
    }
    unsigned long long br = __ballot(isrest);
    if (br) {
      int ldr = __ffsll((unsigned long long)br) - 1;
      int base = 0;
      if (lane == ldr) base = atomicAdd(&cnts[27 + k], __popcll(br));
      base = __shfl(base, ldr);
      if (isrest) {
        int p = base + __popcll(br & ((1ull << lane) - 1ull));
        po_r[k * mcap + p] = o;
        pi_r[k * mcap + p] = i;
      }
    }
  }
}

// --------------------------------------------- MFMA bf16 gather-GEMM-scatter
// Block: 64 pairs x 128 cout (nt0 outer loop, acc register-resident across
// full K), K in 128-wide LDS slabs, B double-buffered 32-wide slices with
// register prefetch. OWNER: plain store; else atomicAdd (launched after).
template<bool OWNER>
__global__ __launch_bounds__(256) void k_conv_mfma(
    const unsigned short* __restrict__ Fb,  // bf16 [rows][cin]
    const short* __restrict__ Wt,           // bf16 [27][cout][cin]
    float* __restrict__ out,
    const int* __restrict__ plo, const int* __restrict__ pli,
    const int* __restrict__ counts, int cin, int cin_pad, int cout, int mcap) {
  int k = blockIdx.z;
  int cnt = counts[k];
  int p0 = blockIdx.x * 64;
  if (p0 >= cnt) return;
  int np = min(64, cnt - p0);

  __shared__ short Alds[64 * 136];      // 128-k slab + 8 pad
  __shared__ short Blds[2][128 * 40];   // 32-k slice + 8 pad, double-buffered
  __shared__ int rows_out[64];
  __shared__ int rows_in[64];

  int tid = threadIdx.x;
  if (tid < 64) {
    rows_out[tid] = (tid < np) ? plo[k * mcap + p0 + tid] : -1;
    rows_in [tid] = (tid < np) ? pli[k * mcap + p0 + tid] : -1;
  }

  int wave = tid >> 6, lane = tid & 63;
  int wm = (wave & 1) * 32, wn = (wave >> 1) * 64;
  int lm = lane & 15, quad = lane >> 4;
  const short* Wk = Wt + (size_t)k * cout * cin;
  int nT = (cout + 127) >> 7;
  int nSlab = (cin_pad + 127) >> 7;

  // B-stage addressing (constant per thread): 2 chunks of 128x32 slice
  int bn0 = (tid) >> 2, bk0 = (tid & 3) << 3;
  int bn1 = (tid + 256) >> 2, bk1 = ((tid + 256) & 3) << 3;

  for (int nt0 = 0; nt0 < nT; ++nt0) {
    int n0 = nt0 << 7;
    f32x4 acc[2][4] = {};
    for (int ks = 0; ks < cin_pad; ks += 128) {
      int kslab = min(128, cin_pad - ks);   // 32/64/128 (pow2 by cin_pad rule)
      int aStride = kslab + 8;
      __syncthreads();  // rows ready (1st pass); Alds/Blds readers done
      if (nSlab > 1 || nt0 == 0) {
        int clog = kslab == 128 ? 4 : (kslab == 64 ? 3 : 2);  // chunks = kslab/8
        for (int u = tid; u < (64 << clog); u += 256) {
          int r = u >> clog;
          int kc = (u - (r << clog)) << 3;
          int gk = ks + kc;
          int irow = rows_in[r];
          short8 v = {0, 0, 0, 0, 0, 0, 0, 0};
          if (irow >= 0 && gk < cin)
            v = *(const short8*)((const short*)Fb + (size_t)irow * cin + gk);
          *(short8*)(Alds + r * aStride + kc) = v;
        }
      }
      int nsl = kslab >> 5;
      // prefetch B slice 0 into regs
      short8 br0 = {0, 0, 0, 0, 0, 0, 0, 0}, br1 = br0;
      {
        int gn = n0 + bn0, gk = ks + bk0;
        if (gn < cout && gk < cin) br0 = *(const short8*)(Wk + (size_t)gn * cin + gk);
        gn = n0 + bn1; gk = ks + bk1;
        if (gn < cout && gk < cin) br1 = *(const short8*)(Wk + (size_t)gn * cin + gk);
      }
      for (int j = 0; j < nsl; ++j) {
        __syncthreads();  // A ready (j==0); Bbuf[j&1] readers (j-2) done
        *(short8*)(&Blds[j & 1][bn0 * 40 + bk0]) = br0;
        *(short8*)(&Blds[j & 1][bn1 * 40 + bk1]) = br1;
        if (j + 1 < nsl) {  // issue next-slice loads; latency hides under MFMA
          int gkbase = ks + (j + 1) * 32;
          short8 z = {0, 0, 0, 0, 0, 0, 0, 0};
          br0 = z; br1 = z;
          int gn = n0 + bn0, gk = gkbase + bk0;
          if (gn < cout && gk < cin) br0 = *(const short8*)(Wk + (size_t)gn * cin + gk);
          gn = n0 + bn1; gk = gkbase + bk1;
          if (gn < cout && gk < cin) br1 = *(const short8*)(Wk + (size_t)gn * cin + gk);
        }
        __syncthreads();  // B visible
        int ka = j * 32 + quad * 8;
        short8 a0 = *(const short8*)(Alds + (wm + lm) * aStride + ka);
        short8 a1 = *(const short8*)(Alds + (wm + 16 + lm) * aStride + ka);
        #pragma unroll
        for (int nt = 0; nt < 4; ++nt) {
          short8 b = *(const short8*)(&Blds[j & 1][(wn + nt * 16 + lm) * 40 + quad * 8]);
          acc[0][nt] = __builtin_amdgcn_mfma_f32_16x16x32_bf16(a0, b, acc[0][nt], 0, 0, 0);
          acc[1][nt] = __builtin_amdgcn_mfma_f32_16x16x32_bf16(a1, b, acc[1][nt], 0, 0, 0);
        }
      }
    }
    #pragma unroll
    for (int mt = 0; mt < 2; ++mt)
      #pragma unroll
      for (int nt = 0; nt < 4; ++nt)
        #pragma unroll
        for (int r = 0; r < 4; ++r) {
          int row = wm + mt * 16 + quad * 4 + r;
          int col = n0 + wn + nt * 16 + lm;
          if (row < np && col < cout) {
            if (OWNER)
              out[(size_t)rows_out[row] * cout + col] = acc[mt][nt][r];
            else
              atomicAdd(&out[(size_t)rows_out[row] * cout + col], acc[mt][nt][r]);
          }
        }
  }
}

// ------------------------------------------- weight convert+transpose to bf16
__global__ void k_convert_w(const float* __restrict__ W, short* __restrict__ Wt,
                            int cin, int cout) {
  __shared__ float tile[32][33];
  int k = blockIdx.z;
  int n0 = blockIdx.x * 32, c0 = blockIdx.y * 32;
  int tx = threadIdx.x & 31, ty = threadIdx.x >> 5;
  const float* Wk = W + (size_t)k * cin * cout;
  for (int i = ty; i < 32; i += 8) {
    int c = c0 + i, n = n0 + tx;
    tile[i][tx] = (c < cin && n < cout) ? Wk[(size_t)c * cout + n] : 0.f;
  }
  __syncthreads();
  short* Wtk = Wt + (size_t)k * cout * cin;
  for (int i = ty; i < 32; i += 8) {
    int n = n0 + i, c = c0 + tx;
    if (n < cout && c < cin) Wtk[(size_t)n * cin + c] = f2bf(tile[tx][i]);
  }
}

// ------------------------------------------------------------------ maxpool
__global__ void k_query_idx(const int* __restrict__ oc, int m, int sh, int Gs,
                            const int* __restrict__ keys, const int* __restrict__ vals,
                            unsigned capmask, int* __restrict__ idx) {
  int t = blockIdx.x * blockDim.x + threadIdx.x;
  if (t >= m * 27) return;
  int o = t / 27, k = t - o * 27;
  int stride = 1 << sh;
  int dx = k / 9 - 1, dy = (k / 3) % 3 - 1, dz = k % 3 - 1;
  int b  = oc[4 * o];
  int qx = oc[4 * o + 1] + dx * stride;
  int qy = oc[4 * o + 2] + dy * stride;
  int qz = oc[4 * o + 3] + dz * stride;
  int res = -1;
  if ((unsigned)qx < GDIM && (unsigned)qy < GDIM && (unsigned)qz < GDIM) {
    int key = ((b * Gs + (qx >> sh)) * Gs + (qy >> sh)) * Gs + (qz >> sh);
    res = hash_lookup(key, keys, vals, capmask);
  }
  idx[t] = res;
}

__global__ void k_maxpool_bn(const float* __restrict__ F, unsigned short* __restrict__ out,
                             const int* __restrict__ idx, int m, int C,
                             const float* __restrict__ ab) {
  long long t = (long long)blockIdx.x * blockDim.x + threadIdx.x;
  if (t >= (long long)m * C) return;
  int o = (int)(t / C), c = (int)(t - (long long)o * C);
  float a = ab[c], b = ab[C + c];
  float best = -3e38f;
  #pragma unroll 1
  for (int k = 0; k < 27; ++k) {
    int i = idx[o * 27 + k];
    if (i >= 0) {
      float y = a * F[(size_t)i * C + c] + b;
      y = fmaxf(y, 0.01f * y);
      best = fmaxf(best, y);
    }
  }
  out[t] = (unsigned short)f2bf(best);
}

// -------------------------------------------------------- slice / gather / mlp
__global__ void k_slice_idx(const int* __restrict__ coords, int n, int sh, int Gs,
                            const int* __restrict__ keys, const int* __restrict__ vals,
                            unsigned capmask, int* __restrict__ sidx) {
  int i = blockIdx.x * blockDim.x + threadIdx.x;
  if (i >= n) return;
  int b = coords[4 * i];
  int key = ((b * Gs + (coords[4 * i + 1] >> sh)) * Gs + (coords[4 * i + 2] >> sh)) * Gs +
            (coords[4 * i + 3] >> sh);
  int v = hash_lookup(key, keys, vals, capmask);
  sidx[i] = (v < 0) ? 0 : v;
}

__global__ void k_gather_cols16(const unsigned short* __restrict__ src, int C,
                                const int* __restrict__ sidx,
                                unsigned short* __restrict__ dst, int dstC, int colOff, int n) {
  long long t = (long long)blockIdx.x * blockDim.x + threadIdx.x;
  if (t >= (long long)n * C) return;
  int o = (int)(t / C), c = (int)(t - (long long)o * C);
  dst[(size_t)o * dstC + colOff + c] = src[(size_t)sidx[o] * C + c];
}

__global__ void k_mlp(const float* __restrict__ feats, const float* __restrict__ w,
                      float* __restrict__ x, int n) {
  int t = blockIdx.x * blockDim.x + threadIdx.x;
  if (t >= n * 32) return;
  x[t] = feats[t >> 5] * w[t & 31];
}

// ----------------------------------------------------------------------- BN
__global__ void k_bn_stats(const float* __restrict__ x, int m, int C, float* __restrict__ sums) {
  int r0 = blockIdx.x * 256;
  int rend = min(r0 + 256, m);
  for (int c = threadIdx.x; c < C; c += 256) {
    float s = 0.f, s2 = 0.f;
    for (int r = r0; r < rend; ++r) {
      float v = x[(size_t)r * C + c];
      s += v; s2 += v * v;
    }
    atomicAdd(&sums[c], s);
    atomicAdd(&sums[C + c], s2);
  }
}

__global__ void k_bn_finalize(const float* __restrict__ sums, const float* __restrict__ gamma,
                              const float* __restrict__ beta, int C, float inv_m,
                              float* __restrict__ ab) {
  for (int c = threadIdx.x; c < C; c += 256) {
    float mu  = sums[c] * inv_m;
    float var = sums[C + c] * inv_m - mu * mu;
    float a = rsqrtf(var + 1e-5f) * gamma[c];
    ab[c] = a;
    ab[C + c] = beta[c] - mu * a;
  }
}

// fused bn+lrelu -> bf16 (pre-conversion for conv inputs)
__global__ void k_bn_bf16(const float* __restrict__ x, unsigned short* __restrict__ xb,
                          long long total, int C, const float* __restrict__ ab) {
  long long t = (long long)blockIdx.x * blockDim.x + threadIdx.x;
  if (t >= total) return;
  int c = (int)(t % C);
  float y = ab[c] * x[t] + ab[C + c];
  y = fmaxf(y, 0.01f * y);
  xb[t] = (unsigned short)f2bf(y);
}

__global__ void k_bn_apply(float* __restrict__ x, long long total, int C,
                           const float* __restrict__ ab) {
  long long t = (long long)blockIdx.x * blockDim.x + threadIdx.x;
  if (t >= total) return;
  int c = (int)(t % C);
  float y = ab[c] * x[t] + ab[C + c];
  x[t] = fmaxf(y, 0.01f * y);
}

// ---------------------------------------------------------------------- host
static inline int cdiv(int a, int b) { return (a + b - 1) / b; }

extern "C" void kernel_launch(void* const* d_in, const int* in_sizes, int n_in,
                              void* d_out, int out_size, void* d_ws, size_t ws_size,
                              hipStream_t stream) {
  (void)n_in; (void)out_size; (void)ws_size;
  const float* feats  = (const float*)d_in[0];
  const int*   coords = (const int*)d_in[1];
  const float* w_mlp = (const float*)d_in[2];
  const float* gm  = (const float*)d_in[3];  const float* bm  = (const float*)d_in[4];
  const float* W1  = (const float*)d_in[5];  const float* g1  = (const float*)d_in[6];  const float* b1  = (const float*)d_in[7];
  const float* W2  = (const float*)d_in[8];  const float* g2  = (const float*)d_in[9];  const float* b2  = (const float*)d_in[10];
  const float* W3  = (const float*)d_in[11]; const float* g3  = (const float*)d_in[12]; const float* b3  = (const float*)d_in[13];
  const float* W4  = (const float*)d_in[14]; const float* g4  = (const float*)d_in[15]; const float* b4  = (const float*)d_in[16];
  const float* W5a = (const float*)d_in[17]; const float* g5a = (const float*)d_in[18]; const float* b5a = (const float*)d_in[19];
  const float* W5b = (const float*)d_in[20]; const float* g5b = (const float*)d_in[21]; const float* b5b = (const float*)d_in[22];
  const float* W5c = (const float*)d_in[23]; const float* g5c = (const float*)d_in[24]; const float* b5c = (const float*)d_in[25];
  const int*   lvl[7];
  for (int i = 0; i < 7; ++i) lvl[i] = (const int*)d_in[26 + i];

  const int N = in_sizes[0];
  int nl[7];
  for (int i = 0; i < 7; ++i) nl[i] = in_sizes[26 + i] / 4;
  const int n2 = nl[0], n4 = nl[1], n8 = nl[2], n16 = nl[3], n32 = nl[4], n64 = nl[5], n128 = nl[6];

  char* ws = (char*)d_ws;
  size_t off = 0;
  auto alloc = [&](size_t bytes) -> char* {
    off = (off + 255) & ~(size_t)255;
    char* p = ws + off;
    off += bytes;
    return p;
  };

  struct Tab { int* keys; int* vals; unsigned mask; int sh; int Gs; int n; const int* src; };
  Tab tab[8];
  const int* tsrc[8] = {coords, lvl[0], lvl[1], lvl[2], lvl[3], lvl[4], lvl[5], lvl[6]};
  int tn[8] = {N, n2, n4, n8, n16, n32, n64, n128};
  for (int i = 0; i < 8; ++i) {
    int cap = 64;
    while (cap < 2 * tn[i]) cap <<= 1;
    tab[i].keys = (int*)alloc((size_t)cap * 4);
    tab[i].vals = (int*)alloc((size_t)cap * 4);
    tab[i].mask = (unsigned)(cap - 1);
    tab[i].sh = i;
    tab[i].Gs = GDIM >> i;
    tab[i].n = tn[i];
    tab[i].src = tsrc[i];
  }

  int* pout   = (int*)alloc((size_t)27 * N * 4);   // owner lists
  int* pin    = (int*)alloc((size_t)27 * N * 4);
  int* pout_r = (int*)alloc((size_t)27 * N * 4);   // rest lists
  int* pin_r  = (int*)alloc((size_t)27 * N * 4);
  int* counts = (int*)alloc(256);                  // [0..26] owner, [27..53] rest
  int* idxbuf = (int*)alloc((size_t)27 * N * 4);
  int* sidx[4];
  for (int i = 0; i < 4; ++i) sidx[i] = (int*)alloc((size_t)N * 4);
  float* bnsum = (float*)alloc(2 * 1024 * 4);
  float* abuf  = (float*)alloc(2 * 1024 * 4);

  auto mxz = [](size_t a, size_t b) { return a > b ? a : b; };
  size_t szA = mxz(mxz((size_t)N * 32, (size_t)n4 * 64), (size_t)n64 * 128) * 4;
  size_t szB = mxz(mxz((size_t)N * 48, (size_t)n16 * 96), (size_t)n2 * 256) * 4;
  float* RA = (float*)alloc(szA);
  float* RB = (float*)alloc(szB);
  float* RG = (float*)alloc((size_t)n4 * 512 * 4);                                 // t5b
  unsigned short* xb  = (unsigned short*)alloc((size_t)N * 32 * 2);
  unsigned short* y1b = (unsigned short*)alloc((size_t)n2 * 48 * 2);
  unsigned short* y2b = (unsigned short*)alloc((size_t)n8 * 64 * 2);
  unsigned short* y3b = (unsigned short*)alloc((size_t)n32 * 96 * 2);
  unsigned short* y4b = (unsigned short*)alloc((size_t)n128 * 128 * 2);
  unsigned short* xcb = (unsigned short*)alloc((size_t)N * 336 * 2);
  unsigned short* t5bb = (unsigned short*)alloc((size_t)n4 * 512 * 2);
  short* Wt1  = (short*)alloc((size_t)27 * 32 * 48 * 2);
  short* Wt2  = (short*)alloc((size_t)27 * 48 * 64 * 2);
  short* Wt3  = (short*)alloc((size_t)27 * 64 * 96 * 2);
  short* Wt4  = (short*)alloc((size_t)27 * 96 * 128 * 2);
  short* Wt5a = (short*)alloc((size_t)27 * 336 * 256 * 2);
  short* Wt5b = (short*)alloc((size_t)27 * 256 * 512 * 2);
  short* Wt5c = (short*)alloc((size_t)27 * 512 * 1024 * 2);

  // hash tables
  for (int i = 0; i < 8; ++i)
    hipMemsetAsync(tab[i].keys, 0xFF, (size_t)(tab[i].mask + 1) * 4, stream);
  for (int i = 0; i < 8; ++i)
    k_build_table<<<cdiv(tab[i].n, 256), 256, 0, stream>>>(
        tab[i].src, tab[i].n, tab[i].sh, tab[i].Gs, tab[i].keys, tab[i].vals, tab[i].mask);

  auto convW = [&](const float* W, short* Wt, int cin, int cout) {
    dim3 g(cdiv(cout, 32), cdiv(cin, 32), 27);
    k_convert_w<<<g, 256, 0, stream>>>(W, Wt, cin, cout);
  };
  convW(W1, Wt1, 32, 48);     convW(W2, Wt2, 48, 64);
  convW(W3, Wt3, 64, 96);     convW(W4, Wt4, 96, 128);
  convW(W5a, Wt5a, 336, 256); convW(W5b, Wt5b, 256, 512);
  convW(W5c, Wt5c, 512, 1024);

  auto conv = [&](const unsigned short* Fb, const short* Wt, const int* oc, int m,
                  const Tab& t, int cin, int cout, float* out) {
    hipMemsetAsync(counts, 0, 54 * 4, stream);
    dim3 gq(cdiv(m, 256), 27);
    k_query_idx_t<<<gq, 256, 0, stream>>>(oc, m, t.sh, t.Gs, t.keys, t.vals, t.mask, idxbuf);
    k_make_pairs<<<cdiv(m, 256), 256, 0, stream>>>(idxbuf, m, pout, pin, pout_r, pin_r,
                                                   counts, N);
    int cin_pad = cin <= 32 ? 32 : (cin <= 64 ? 64 : ((cin + 127) & ~127));
    dim3 grid(cdiv(m, 64), 1, 27);
    // owner first (plain stores initialize out), then rest (atomics), in stream order
    k_conv_mfma<true><<<grid, 256, 0, stream>>>(Fb, Wt, out, pout, pin, counts,
                                                cin, cin_pad, cout, N);
    k_conv_mfma<false><<<grid, 256, 0, stream>>>(Fb, Wt, out, pout_r, pin_r, counts + 27,
                                                 cin, cin_pad, cout, N);
  };
  auto stats = [&](const float* x, int m, int C, const float* gamma, const float* beta) {
    hipMemsetAsync(bnsum, 0, (size_t)2 * C * 4, stream);
    k_bn_stats<<<cdiv(m, 256), 256, 0, stream>>>(x, m, C, bnsum);
    k_bn_finalize<<<1, 256, 0, stream>>>(bnsum, gamma, beta, C, 1.0f / (float)m, abuf);
  };
  auto pool = [&](const float* F, const int* oc, int m, const Tab& t, int C,
                  unsigned short* out) {
    k_query_idx<<<cdiv(m * 27, 256), 256, 0, stream>>>(
        oc, m, t.sh, t.Gs, t.keys, t.vals, t.mask, idxbuf);
    long long total = (long long)m * C;
    k_maxpool_bn<<<(int)((total + 255) / 256), 256, 0, stream>>>(F, out, idxbuf, m, C, abuf);
  };
  auto cvt = [&](const float* src, unsigned short* dst, long long total, int C) {
    k_bn_bf16<<<(int)((total + 255) / 256), 256, 0, stream>>>(src, dst, total, C, abuf);
  };

  // ---- network ----
  float* x = RA;
  k_mlp<<<cdiv(N * 32, 256), 256, 0, stream>>>(feats, w_mlp, x, N);
  stats(x, N, 32, gm, bm);
  cvt(x, xb, (long long)N * 32, 32);                    // bn(mlp)+lrelu -> bf16

  float* t1 = RB;
  conv(xb, Wt1, coords, N, tab[0], 32, 48, t1);
  stats(t1, N, 48, g1, b1);
  pool(t1, lvl[0], n2, tab[0], 48, y1b);

  float* t2 = RA;
  conv(y1b, Wt2, lvl[1], n4, tab[1], 48, 64, t2);
  stats(t2, n4, 64, g2, b2);
  pool(t2, lvl[2], n8, tab[2], 64, y2b);

  float* t3 = RB;
  conv(y2b, Wt3, lvl[3], n16, tab[3], 64, 96, t3);
  stats(t3, n16, 96, g3, b3);
  pool(t3, lvl[4], n32, tab[4], 96, y3b);

  float* t4 = RA;
  conv(y3b, Wt4, lvl[5], n64, tab[5], 96, 128, t4);
  stats(t4, n64, 128, g4, b4);
  pool(t4, lvl[6], n128, tab[6], 128, y4b);

  // slice_to_field -> xcb (bf16)
  k_slice_idx<<<cdiv(N, 256), 256, 0, stream>>>(coords, N, tab[1].sh, tab[1].Gs,
                                                tab[1].keys, tab[1].vals, tab[1].mask, sidx[0]);
  k_slice_idx<<<cdiv(N, 256), 256, 0, stream>>>(coords, N, tab[3].sh, tab[3].Gs,
                                                tab[3].keys, tab[3].vals, tab[3].mask, sidx[1]);
  k_slice_idx<<<cdiv(N, 256), 256, 0, stream>>>(coords, N, tab[5].sh, tab[5].Gs,
                                                tab[5].keys, tab[5].vals, tab[5].mask, sidx[2]);
  k_slice_idx<<<cdiv(N, 256), 256, 0, stream>>>(coords, N, tab[7].sh, tab[7].Gs,
                                                tab[7].keys, tab[7].vals, tab[7].mask, sidx[3]);
  k_gather_cols16<<<(int)(((long long)N * 48 + 255) / 256), 256, 0, stream>>>(y1b, 48, sidx[0], xcb, 336, 0, N);
  k_gather_cols16<<<(int)(((long long)N * 64 + 255) / 256), 256, 0, stream>>>(y2b, 64, sidx[1], xcb, 336, 48, N);
  k_gather_cols16<<<(int)(((long long)N * 96 + 255) / 256), 256, 0, stream>>>(y3b, 96, sidx[2], xcb, 336, 112, N);
  k_gather_cols16<<<(int)(((long long)N * 128 + 255) / 256), 256, 0, stream>>>(y4b, 128, sidx[3], xcb, 336, 208, N);

  float* t5a = RB;
  conv(xcb, Wt5a, lvl[0], n2, tab[0], 336, 256, t5a);
  stats(t5a, n2, 256, g5a, b5a);
  unsigned short* t5ab = xcb;  // xcb free after conv5a; n2*256*2 <= N*336*2
  cvt(t5a, t5ab, (long long)n2 * 256, 256);

  float* t5b = RG;
  conv(t5ab, Wt5b, lvl[1], n4, tab[1], 256, 512, t5b);
  stats(t5b, n4, 512, g5b, b5b);
  cvt(t5b, t5bb, (long long)n4 * 512, 512);

  float* outp = (float*)d_out;
  conv(t5bb, Wt5c, lvl[2], n8, tab[2], 512, 1024, outp);
  stats(outp, n8, 1024, g5c, b5c);
  long long total = (long long)n8 * 1024;
  k_bn_apply<<<(int)((total + 255) / 256), 256, 0, stream>>>(outp, total, 1024, abuf);
}

// Round 3
// 1960.105 us; speedup vs baseline: 1.3299x; 1.3299x over previous
//
#include <hip/hip_runtime.h>
#include <cstdint>
#include <cstddef>

#define GDIM 512

typedef __attribute__((ext_vector_type(8))) short short8;
typedef __attribute__((ext_vector_type(4))) float f32x4;
typedef __attribute__((ext_vector_type(4))) unsigned short ushort4v;

__device__ __forceinline__ short f2bf(float f) {
  unsigned u = __float_as_uint(f);
  u = u + 0x7fffu + ((u >> 16) & 1u);  // round-to-nearest-even
  return (short)(u >> 16);
}

// ---------------------------------------------------------------- hash table
__device__ __forceinline__ int hash_lookup(int key, const int* __restrict__ keys,
                                           const int* __restrict__ vals, unsigned capmask) {
  unsigned slot = ((unsigned)key * 2654435761u) & capmask;
  while (true) {
    int kk = keys[slot];
    if (kk == key) return vals[slot];
    if (kk == -1) return -1;
    slot = (slot + 1) & capmask;
  }
}

__global__ void k_build_table(const int* __restrict__ coords, int n, int sh, int Gs,
                              int* __restrict__ keys, int* __restrict__ vals, unsigned capmask) {
  int i = blockIdx.x * blockDim.x + threadIdx.x;
  if (i >= n) return;
  int b = coords[4 * i];
  int key = ((b * Gs + (coords[4 * i + 1] >> sh)) * Gs + (coords[4 * i + 2] >> sh)) * Gs +
            (coords[4 * i + 3] >> sh);
  unsigned slot = ((unsigned)key * 2654435761u) & capmask;
  while (true) {
    int prev = atomicCAS(&keys[slot], -1, key);
    if (prev == -1) { vals[slot] = i; return; }
    slot = (slot + 1) & capmask;
  }
}

// ---------------------------------------------- conv: idxT (transposed query)
__global__ void k_query_idx_t(const int* __restrict__ oc, int m, int sh, int Gs,
                              const int* __restrict__ keys, const int* __restrict__ vals,
                              unsigned capmask, int* __restrict__ idxT) {
  int k = blockIdx.y;
  int o = blockIdx.x * blockDim.x + threadIdx.x;
  if (o >= m) return;
  int stride = 1 << sh;
  int dx = k / 9 - 1, dy = (k / 3) % 3 - 1, dz = k % 3 - 1;
  int4 c = *(const int4*)(oc + 4 * o);
  int qx = c.y + dx * stride;
  int qy = c.z + dy * stride;
  int qz = c.w + dz * stride;
  int res = -1;
  if ((unsigned)qx < GDIM && (unsigned)qy < GDIM && (unsigned)qz < GDIM) {
    int key = ((c.x * Gs + (qx >> sh)) * Gs + (qy >> sh)) * Gs + (qz >> sh);
    res = hash_lookup(key, keys, vals, capmask);
  }
  idxT[(size_t)k * m + o] = res;
}

// Split pairs into owner (first hit per output) and rest. Every output has
// >=1 hit (its own child cell), so owner GEMM plain-stores.
__global__ void k_make_pairs(const int* __restrict__ idxT, int m,
                             int* __restrict__ po_o, int* __restrict__ pi_o,
                             int* __restrict__ po_r, int* __restrict__ pi_r,
                             int* __restrict__ cnts, int mcap) {
  int o = blockIdx.x * blockDim.x + threadIdx.x;
  bool act = o < m;
  int lane = threadIdx.x & 63;
  bool owned = false;
  for (int k = 0; k < 27; ++k) {
    int i = act ? idxT[(size_t)k * m + o] : -1;
    bool hit = i >= 0;
    bool isown = hit && !owned;
    if (isown) owned = true;
    bool isrest = hit && !isown;
    unsigned long long bo = __ballot(isown);
    if (bo) {
      int ldr = __ffsll((unsigned long long)bo) - 1;
      int base = 0;
      if (lane == ldr) base = atomicAdd(&cnts[k], __popcll(bo));
      base = __shfl(base, ldr);
      if (isown) {
        int p = base + __popcll(bo & ((1ull << lane) - 1ull));
        po_o[k * mcap + p] = o;
        pi_o[k * mcap + p] = i;
      }
    }
    unsigned long long br = __ballot(isrest);
    if (br) {
      int ldr = __ffsll((unsigned long long)br) - 1;
      int base = 0;
      if (lane == ldr) base = atomicAdd(&cnts[27 + k], __popcll(br));
      base = __shfl(base, ldr);
      if (isrest) {
        int p = base + __popcll(br & ((1ull << lane) - 1ull));
        po_r[k * mcap + p] = o;
        pi_r[k * mcap + p] = i;
      }
    }
  }
}

// --------------------------------------------- MFMA bf16 gather-GEMM-scatter
template<bool OWNER>
__global__ __launch_bounds__(256) void k_conv_mfma(
    const unsigned short* __restrict__ Fb,  // bf16 [rows][cin]
    const short* __restrict__ Wt,           // bf16 [27][cout][cin]
    float* __restrict__ out,
    const int* __restrict__ plo, const int* __restrict__ pli,
    const int* __restrict__ counts, int cin, int cin_pad, int cout, int mcap) {
  int k = blockIdx.z;
  int cnt = counts[k];
  int p0 = blockIdx.x * 64;
  if (p0 >= cnt) return;
  int np = min(64, cnt - p0);

  __shared__ short Alds[64 * 136];      // 128-k slab + 8 pad
  __shared__ short Blds[2][128 * 40];   // 32-k slice + 8 pad, double-buffered
  __shared__ int rows_out[64];
  __shared__ int rows_in[64];

  int tid = threadIdx.x;
  if (tid < 64) {
    rows_out[tid] = (tid < np) ? plo[k * mcap + p0 + tid] : -1;
    rows_in [tid] = (tid < np) ? pli[k * mcap + p0 + tid] : -1;
  }

  int wave = tid >> 6, lane = tid & 63;
  int wm = (wave & 1) * 32, wn = (wave >> 1) * 64;
  int lm = lane & 15, quad = lane >> 4;
  const short* Wk = Wt + (size_t)k * cout * cin;
  int nT = (cout + 127) >> 7;
  int nSlab = (cin_pad + 127) >> 7;

  int bn0 = (tid) >> 2, bk0 = (tid & 3) << 3;
  int bn1 = (tid + 256) >> 2, bk1 = ((tid + 256) & 3) << 3;

  for (int nt0 = 0; nt0 < nT; ++nt0) {
    int n0 = nt0 << 7;
    f32x4 acc[2][4] = {};
    for (int ks = 0; ks < cin_pad; ks += 128) {
      int kslab = min(128, cin_pad - ks);
      int aStride = kslab + 8;
      __syncthreads();
      if (nSlab > 1 || nt0 == 0) {
        int clog = kslab == 128 ? 4 : (kslab == 64 ? 3 : 2);
        for (int u = tid; u < (64 << clog); u += 256) {
          int r = u >> clog;
          int kc = (u - (r << clog)) << 3;
          int gk = ks + kc;
          int irow = rows_in[r];
          short8 v = {0, 0, 0, 0, 0, 0, 0, 0};
          if (irow >= 0 && gk < cin)
            v = *(const short8*)((const short*)Fb + (size_t)irow * cin + gk);
          *(short8*)(Alds + r * aStride + kc) = v;
        }
      }
      int nsl = kslab >> 5;
      short8 br0 = {0, 0, 0, 0, 0, 0, 0, 0}, br1 = br0;
      {
        int gn = n0 + bn0, gk = ks + bk0;
        if (gn < cout && gk < cin) br0 = *(const short8*)(Wk + (size_t)gn * cin + gk);
        gn = n0 + bn1; gk = ks + bk1;
        if (gn < cout && gk < cin) br1 = *(const short8*)(Wk + (size_t)gn * cin + gk);
      }
      for (int j = 0; j < nsl; ++j) {
        __syncthreads();
        *(short8*)(&Blds[j & 1][bn0 * 40 + bk0]) = br0;
        *(short8*)(&Blds[j & 1][bn1 * 40 + bk1]) = br1;
        if (j + 1 < nsl) {
          int gkbase = ks + (j + 1) * 32;
          short8 z = {0, 0, 0, 0, 0, 0, 0, 0};
          br0 = z; br1 = z;
          int gn = n0 + bn0, gk = gkbase + bk0;
          if (gn < cout && gk < cin) br0 = *(const short8*)(Wk + (size_t)gn * cin + gk);
          gn = n0 + bn1; gk = gkbase + bk1;
          if (gn < cout && gk < cin) br1 = *(const short8*)(Wk + (size_t)gn * cin + gk);
        }
        __syncthreads();
        int ka = j * 32 + quad * 8;
        short8 a0 = *(const short8*)(Alds + (wm + lm) * aStride + ka);
        short8 a1 = *(const short8*)(Alds + (wm + 16 + lm) * aStride + ka);
        #pragma unroll
        for (int nt = 0; nt < 4; ++nt) {
          short8 b = *(const short8*)(&Blds[j & 1][(wn + nt * 16 + lm) * 40 + quad * 8]);
          acc[0][nt] = __builtin_amdgcn_mfma_f32_16x16x32_bf16(a0, b, acc[0][nt], 0, 0, 0);
          acc[1][nt] = __builtin_amdgcn_mfma_f32_16x16x32_bf16(a1, b, acc[1][nt], 0, 0, 0);
        }
      }
    }
    #pragma unroll
    for (int mt = 0; mt < 2; ++mt)
      #pragma unroll
      for (int nt = 0; nt < 4; ++nt)
        #pragma unroll
        for (int r = 0; r < 4; ++r) {
          int row = wm + mt * 16 + quad * 4 + r;
          int col = n0 + wn + nt * 16 + lm;
          if (row < np && col < cout) {
            if (OWNER)
              out[(size_t)rows_out[row] * cout + col] = acc[mt][nt][r];
            else
              atomicAdd(&out[(size_t)rows_out[row] * cout + col], acc[mt][nt][r]);
          }
        }
  }
}

// ------------------------------------------- weight convert+transpose to bf16
__global__ void k_convert_w(const float* __restrict__ W, short* __restrict__ Wt,
                            int cin, int cout) {
  __shared__ float tile[32][33];
  int k = blockIdx.z;
  int n0 = blockIdx.x * 32, c0 = blockIdx.y * 32;
  int tx = threadIdx.x & 31, ty = threadIdx.x >> 5;
  const float* Wk = W + (size_t)k * cin * cout;
  for (int i = ty; i < 32; i += 8) {
    int c = c0 + i, n = n0 + tx;
    tile[i][tx] = (c < cin && n < cout) ? Wk[(size_t)c * cout + n] : 0.f;
  }
  __syncthreads();
  short* Wtk = Wt + (size_t)k * cout * cin;
  for (int i = ty; i < 32; i += 8) {
    int n = n0 + i, c = c0 + tx;
    if (n < cout && c < cin) Wtk[(size_t)n * cin + c] = f2bf(tile[tx][i]);
  }
}

// ------------------------------------------------------------------ maxpool
__global__ void k_query_idx(const int* __restrict__ oc, int m, int sh, int Gs,
                            const int* __restrict__ keys, const int* __restrict__ vals,
                            unsigned capmask, int* __restrict__ idx) {
  int t = blockIdx.x * blockDim.x + threadIdx.x;
  if (t >= m * 27) return;
  int o = t / 27, k = t - o * 27;
  int stride = 1 << sh;
  int dx = k / 9 - 1, dy = (k / 3) % 3 - 1, dz = k % 3 - 1;
  int b  = oc[4 * o];
  int qx = oc[4 * o + 1] + dx * stride;
  int qy = oc[4 * o + 2] + dy * stride;
  int qz = oc[4 * o + 3] + dz * stride;
  int res = -1;
  if ((unsigned)qx < GDIM && (unsigned)qy < GDIM && (unsigned)qz < GDIM) {
    int key = ((b * Gs + (qx >> sh)) * Gs + (qy >> sh)) * Gs + (qz >> sh);
    res = hash_lookup(key, keys, vals, capmask);
  }
  idx[t] = res;
}

__global__ void k_maxpool_bn(const float* __restrict__ F, unsigned short* __restrict__ out,
                             const int* __restrict__ idx, int m, int C,
                             const float* __restrict__ ab) {
  long long t = (long long)blockIdx.x * blockDim.x + threadIdx.x;
  if (t >= (long long)m * C) return;
  int o = (int)(t / C), c = (int)(t - (long long)o * C);
  float a = ab[c], b = ab[C + c];
  float best = -3e38f;
  #pragma unroll 1
  for (int k = 0; k < 27; ++k) {
    int i = idx[o * 27 + k];
    if (i >= 0) {
      float y = a * F[(size_t)i * C + c] + b;
      y = fmaxf(y, 0.01f * y);
      best = fmaxf(best, y);
    }
  }
  out[t] = (unsigned short)f2bf(best);
}

// -------------------------------------------------------- slice / gather / mlp
__global__ void k_slice_idx(const int* __restrict__ coords, int n, int sh, int Gs,
                            const int* __restrict__ keys, const int* __restrict__ vals,
                            unsigned capmask, int* __restrict__ sidx) {
  int i = blockIdx.x * blockDim.x + threadIdx.x;
  if (i >= n) return;
  int b = coords[4 * i];
  int key = ((b * Gs + (coords[4 * i + 1] >> sh)) * Gs + (coords[4 * i + 2] >> sh)) * Gs +
            (coords[4 * i + 3] >> sh);
  int v = hash_lookup(key, keys, vals, capmask);
  sidx[i] = (v < 0) ? 0 : v;
}

__global__ void k_gather_cols16(const unsigned short* __restrict__ src, int C,
                                const int* __restrict__ sidx,
                                unsigned short* __restrict__ dst, int dstC, int colOff, int n) {
  long long t = (long long)blockIdx.x * blockDim.x + threadIdx.x;
  if (t >= (long long)n * C) return;
  int o = (int)(t / C), c = (int)(t - (long long)o * C);
  dst[(size_t)o * dstC + colOff + c] = src[(size_t)sidx[o] * C + c];
}

__global__ void k_mlp(const float* __restrict__ feats, const float* __restrict__ w,
                      float* __restrict__ x, int n) {
  int t = blockIdx.x * blockDim.x + threadIdx.x;
  if (t >= n * 32) return;
  x[t] = feats[t >> 5] * w[t & 31];
}

// ----------------------------------------------------------------------- BN
// 2D-parallel column stats. grid (NS, CG):
//  C>=256: each block owns 256 cols (blockIdx.y) over a row stripe, RL=1.
//  C<256 : CG=1, RL=256/C row-lanes per column, LDS-reduced before atomic.
__global__ void k_bn_stats(const float* __restrict__ x, int m, int C,
                           float* __restrict__ sums) {
  __shared__ float ls[2][256];
  int tid = threadIdx.x;
  int RL = (C >= 256) ? 1 : (256 / C);
  int c, rl;
  bool active;
  if (C >= 256) { c = blockIdx.y * 256 + tid; rl = 0; active = true; }
  else { c = tid % C; rl = tid / C; active = (tid < RL * C); }
  float s = 0.f, s2 = 0.f;
  if (active) {
    int step = gridDim.x * RL;
    for (int r = blockIdx.x * RL + rl; r < m; r += step) {
      float v = x[(size_t)r * C + c];
      s += v; s2 += v * v;
    }
  }
  if (RL == 1) {
    atomicAdd(&sums[c], s);
    atomicAdd(&sums[C + c], s2);
  } else {
    ls[0][tid] = s; ls[1][tid] = s2;
    __syncthreads();
    if (tid < C) {
      for (int j = 1; j < RL; ++j) { s += ls[0][c + j * C]; s2 += ls[1][c + j * C]; }
      atomicAdd(&sums[c], s);
      atomicAdd(&sums[C + c], s2);
    }
  }
}

__global__ void k_bn_finalize(const float* __restrict__ sums, const float* __restrict__ gamma,
                              const float* __restrict__ beta, int C, float inv_m,
                              float* __restrict__ ab) {
  for (int c = threadIdx.x; c < C; c += 256) {
    float mu  = sums[c] * inv_m;
    float var = sums[C + c] * inv_m - mu * mu;
    float a = rsqrtf(var + 1e-5f) * gamma[c];
    ab[c] = a;
    ab[C + c] = beta[c] - mu * a;
  }
}

// fused bn+lrelu -> bf16, float4/ushort4 vectorized (C % 4 == 0)
__global__ void k_bn_bf16(const float* __restrict__ x, unsigned short* __restrict__ xb,
                          long long total4, int C, const float* __restrict__ ab) {
  long long t = (long long)blockIdx.x * blockDim.x + threadIdx.x;
  if (t >= total4) return;
  long long e = t * 4;
  int c = (int)(e % C);
  float4 v = *(const float4*)(x + e);
  ushort4v o;
  float y0 = ab[c] * v.x + ab[C + c];         o.x = (unsigned short)f2bf(fmaxf(y0, 0.01f * y0));
  float y1 = ab[c + 1] * v.y + ab[C + c + 1]; o.y = (unsigned short)f2bf(fmaxf(y1, 0.01f * y1));
  float y2 = ab[c + 2] * v.z + ab[C + c + 2]; o.z = (unsigned short)f2bf(fmaxf(y2, 0.01f * y2));
  float y3 = ab[c + 3] * v.w + ab[C + c + 3]; o.w = (unsigned short)f2bf(fmaxf(y3, 0.01f * y3));
  *(ushort4v*)(xb + e) = o;
}

__global__ void k_bn_apply(float* __restrict__ x, long long total4, int C,
                           const float* __restrict__ ab) {
  long long t = (long long)blockIdx.x * blockDim.x + threadIdx.x;
  if (t >= total4) return;
  long long e = t * 4;
  int c = (int)(e % C);
  float4 v = *(const float4*)(x + e);
  float y0 = ab[c] * v.x + ab[C + c];         v.x = fmaxf(y0, 0.01f * y0);
  float y1 = ab[c + 1] * v.y + ab[C + c + 1]; v.y = fmaxf(y1, 0.01f * y1);
  float y2 = ab[c + 2] * v.z + ab[C + c + 2]; v.z = fmaxf(y2, 0.01f * y2);
  float y3 = ab[c + 3] * v.w + ab[C + c + 3]; v.w = fmaxf(y3, 0.01f * y3);
  *(float4*)(x + e) = v;
}

// ---------------------------------------------------------------------- host
static inline int cdiv(int a, int b) { return (a + b - 1) / b; }

extern "C" void kernel_launch(void* const* d_in, const int* in_sizes, int n_in,
                              void* d_out, int out_size, void* d_ws, size_t ws_size,
                              hipStream_t stream) {
  (void)n_in; (void)out_size; (void)ws_size;
  const float* feats  = (const float*)d_in[0];
  const int*   coords = (const int*)d_in[1];
  const float* w_mlp = (const float*)d_in[2];
  const float* gm  = (const float*)d_in[3];  const float* bm  = (const float*)d_in[4];
  const float* W1  = (const float*)d_in[5];  const float* g1  = (const float*)d_in[6];  const float* b1  = (const float*)d_in[7];
  const float* W2  = (const float*)d_in[8];  const float* g2  = (const float*)d_in[9];  const float* b2  = (const float*)d_in[10];
  const float* W3  = (const float*)d_in[11]; const float* g3  = (const float*)d_in[12]; const float* b3  = (const float*)d_in[13];
  const float* W4  = (const float*)d_in[14]; const float* g4  = (const float*)d_in[15]; const float* b4  = (const float*)d_in[16];
  const float* W5a = (const float*)d_in[17]; const float* g5a = (const float*)d_in[18]; const float* b5a = (const float*)d_in[19];
  const float* W5b = (const float*)d_in[20]; const float* g5b = (const float*)d_in[21]; const float* b5b = (const float*)d_in[22];
  const float* W5c = (const float*)d_in[23]; const float* g5c = (const float*)d_in[24]; const float* b5c = (const float*)d_in[25];
  const int*   lvl[7];
  for (int i = 0; i < 7; ++i) lvl[i] = (const int*)d_in[26 + i];

  const int N = in_sizes[0];
  int nl[7];
  for (int i = 0; i < 7; ++i) nl[i] = in_sizes[26 + i] / 4;
  const int n2 = nl[0], n4 = nl[1], n8 = nl[2], n16 = nl[3], n32 = nl[4], n64 = nl[5], n128 = nl[6];

  char* ws = (char*)d_ws;
  size_t off = 0;
  auto alloc = [&](size_t bytes) -> char* {
    off = (off + 255) & ~(size_t)255;
    char* p = ws + off;
    off += bytes;
    return p;
  };

  struct Tab { int* keys; int* vals; unsigned mask; int sh; int Gs; int n; const int* src; };
  Tab tab[8];
  const int* tsrc[8] = {coords, lvl[0], lvl[1], lvl[2], lvl[3], lvl[4], lvl[5], lvl[6]};
  int tn[8] = {N, n2, n4, n8, n16, n32, n64, n128};
  for (int i = 0; i < 8; ++i) {
    int cap = 64;
    while (cap < 2 * tn[i]) cap <<= 1;
    tab[i].keys = (int*)alloc((size_t)cap * 4);
    tab[i].vals = (int*)alloc((size_t)cap * 4);
    tab[i].mask = (unsigned)(cap - 1);
    tab[i].sh = i;
    tab[i].Gs = GDIM >> i;
    tab[i].n = tn[i];
    tab[i].src = tsrc[i];
  }

  int* pout   = (int*)alloc((size_t)27 * N * 4);   // owner lists
  int* pin    = (int*)alloc((size_t)27 * N * 4);
  int* pout_r = (int*)alloc((size_t)27 * N * 4);   // rest lists
  int* pin_r  = (int*)alloc((size_t)27 * N * 4);
  int* counts = (int*)alloc(256);                  // [0..26] owner, [27..53] rest
  int* idxbuf = (int*)alloc((size_t)27 * N * 4);
  int* sidx[4];
  for (int i = 0; i < 4; ++i) sidx[i] = (int*)alloc((size_t)N * 4);
  float* bnsum = (float*)alloc(2 * 1024 * 4);
  float* abuf  = (float*)alloc(2 * 1024 * 4);

  auto mxz = [](size_t a, size_t b) { return a > b ? a : b; };
  size_t szA = mxz(mxz((size_t)N * 32, (size_t)n4 * 64), (size_t)n64 * 128) * 4;
  size_t szB = mxz(mxz((size_t)N * 48, (size_t)n16 * 96), (size_t)n2 * 256) * 4;
  float* RA = (float*)alloc(szA);
  float* RB = (float*)alloc(szB);
  float* RG = (float*)alloc((size_t)n4 * 512 * 4);                                 // t5b
  unsigned short* xb  = (unsigned short*)alloc((size_t)N * 32 * 2);
  unsigned short* y1b = (unsigned short*)alloc((size_t)n2 * 48 * 2);
  unsigned short* y2b = (unsigned short*)alloc((size_t)n8 * 64 * 2);
  unsigned short* y3b = (unsigned short*)alloc((size_t)n32 * 96 * 2);
  unsigned short* y4b = (unsigned short*)alloc((size_t)n128 * 128 * 2);
  unsigned short* xcb = (unsigned short*)alloc((size_t)N * 336 * 2);
  unsigned short* t5bb = (unsigned short*)alloc((size_t)n4 * 512 * 2);
  short* Wt1  = (short*)alloc((size_t)27 * 32 * 48 * 2);
  short* Wt2  = (short*)alloc((size_t)27 * 48 * 64 * 2);
  short* Wt3  = (short*)alloc((size_t)27 * 64 * 96 * 2);
  short* Wt4  = (short*)alloc((size_t)27 * 96 * 128 * 2);
  short* Wt5a = (short*)alloc((size_t)27 * 336 * 256 * 2);
  short* Wt5b = (short*)alloc((size_t)27 * 256 * 512 * 2);
  short* Wt5c = (short*)alloc((size_t)27 * 512 * 1024 * 2);

  // hash tables
  for (int i = 0; i < 8; ++i)
    hipMemsetAsync(tab[i].keys, 0xFF, (size_t)(tab[i].mask + 1) * 4, stream);
  for (int i = 0; i < 8; ++i)
    k_build_table<<<cdiv(tab[i].n, 256), 256, 0, stream>>>(
        tab[i].src, tab[i].n, tab[i].sh, tab[i].Gs, tab[i].keys, tab[i].vals, tab[i].mask);

  auto convW = [&](const float* W, short* Wt, int cin, int cout) {
    dim3 g(cdiv(cout, 32), cdiv(cin, 32), 27);
    k_convert_w<<<g, 256, 0, stream>>>(W, Wt, cin, cout);
  };
  convW(W1, Wt1, 32, 48);     convW(W2, Wt2, 48, 64);
  convW(W3, Wt3, 64, 96);     convW(W4, Wt4, 96, 128);
  convW(W5a, Wt5a, 336, 256); convW(W5b, Wt5b, 256, 512);
  convW(W5c, Wt5c, 512, 1024);

  auto conv = [&](const unsigned short* Fb, const short* Wt, const int* oc, int m,
                  const Tab& t, int cin, int cout, float* out) {
    hipMemsetAsync(counts, 0, 54 * 4, stream);
    dim3 gq(cdiv(m, 256), 27);
    k_query_idx_t<<<gq, 256, 0, stream>>>(oc, m, t.sh, t.Gs, t.keys, t.vals, t.mask, idxbuf);
    k_make_pairs<<<cdiv(m, 256), 256, 0, stream>>>(idxbuf, m, pout, pin, pout_r, pin_r,
                                                   counts, N);
    int cin_pad = cin <= 32 ? 32 : (cin <= 64 ? 64 : ((cin + 127) & ~127));
    dim3 grid(cdiv(m, 64), 1, 27);
    k_conv_mfma<true><<<grid, 256, 0, stream>>>(Fb, Wt, out, pout, pin, counts,
                                                cin, cin_pad, cout, N);
    k_conv_mfma<false><<<grid, 256, 0, stream>>>(Fb, Wt, out, pout_r, pin_r, counts + 27,
                                                 cin, cin_pad, cout, N);
  };
  auto stats = [&](const float* x, int m, int C, const float* gamma, const float* beta) {
    hipMemsetAsync(bnsum, 0, (size_t)2 * C * 4, stream);
    int CG = (C >= 256) ? (C / 256) : 1;
    int RL = (C >= 256) ? 1 : (256 / C);
    int NS = (C >= 256) ? 512 : 256;
    int maxNS = cdiv(m, RL);
    if (NS > maxNS) NS = maxNS < 1 ? 1 : maxNS;
    dim3 g(NS, CG);
    k_bn_stats<<<g, 256, 0, stream>>>(x, m, C, bnsum);
    k_bn_finalize<<<1, 256, 0, stream>>>(bnsum, gamma, beta, C, 1.0f / (float)m, abuf);
  };
  auto pool = [&](const float* F, const int* oc, int m, const Tab& t, int C,
                  unsigned short* out) {
    k_query_idx<<<cdiv(m * 27, 256), 256, 0, stream>>>(
        oc, m, t.sh, t.Gs, t.keys, t.vals, t.mask, idxbuf);
    long long total = (long long)m * C;
    k_maxpool_bn<<<(int)((total + 255) / 256), 256, 0, stream>>>(F, out, idxbuf, m, C, abuf);
  };
  auto cvt = [&](const float* src, unsigned short* dst, long long total, int C) {
    long long t4 = total / 4;
    k_bn_bf16<<<(int)((t4 + 255) / 256), 256, 0, stream>>>(src, dst, t4, C, abuf);
  };

  // ---- network ----
  float* x = RA;
  k_mlp<<<cdiv(N * 32, 256), 256, 0, stream>>>(feats, w_mlp, x, N);
  stats(x, N, 32, gm, bm);
  cvt(x, xb, (long long)N * 32, 32);                    // bn(mlp)+lrelu -> bf16

  float* t1 = RB;
  conv(xb, Wt1, coords, N, tab[0], 32, 48, t1);
  stats(t1, N, 48, g1, b1);
  pool(t1, lvl[0], n2, tab[0], 48, y1b);

  float* t2 = RA;
  conv(y1b, Wt2, lvl[1], n4, tab[1], 48, 64, t2);
  stats(t2, n4, 64, g2, b2);
  pool(t2, lvl[2], n8, tab[2], 64, y2b);

  float* t3 = RB;
  conv(y2b, Wt3, lvl[3], n16, tab[3], 64, 96, t3);
  stats(t3, n16, 96, g3, b3);
  pool(t3, lvl[4], n32, tab[4], 96, y3b);

  float* t4 = RA;
  conv(y3b, Wt4, lvl[5], n64, tab[5], 96, 128, t4);
  stats(t4, n64, 128, g4, b4);
  pool(t4, lvl[6], n128, tab[6], 128, y4b);

  // slice_to_field -> xcb (bf16)
  k_slice_idx<<<cdiv(N, 256), 256, 0, stream>>>(coords, N, tab[1].sh, tab[1].Gs,
                                                tab[1].keys, tab[1].vals, tab[1].mask, sidx[0]);
  k_slice_idx<<<cdiv(N, 256), 256, 0, stream>>>(coords, N, tab[3].sh, tab[3].Gs,
                                                tab[3].keys, tab[3].vals, tab[3].mask, sidx[1]);
  k_slice_idx<<<cdiv(N, 256), 256, 0, stream>>>(coords, N, tab[5].sh, tab[5].Gs,
                                                tab[5].keys, tab[5].vals, tab[5].mask, sidx[2]);
  k_slice_idx<<<cdiv(N, 256), 256, 0, stream>>>(coords, N, tab[7].sh, tab[7].Gs,
                                                tab[7].keys, tab[7].vals, tab[7].mask, sidx[3]);
  k_gather_cols16<<<(int)(((long long)N * 48 + 255) / 256), 256, 0, stream>>>(y1b, 48, sidx[0], xcb, 336, 0, N);
  k_gather_cols16<<<(int)(((long long)N * 64 + 255) / 256), 256, 0, stream>>>(y2b, 64, sidx[1], xcb, 336, 48, N);
  k_gather_cols16<<<(int)(((long long)N * 96 + 255) / 256), 256, 0, stream>>>(y3b, 96, sidx[2], xcb, 336, 112, N);
  k_gather_cols16<<<(int)(((long long)N * 128 + 255) / 256), 256, 0, stream>>>(y4b, 128, sidx[3], xcb, 336, 208, N);

  float* t5a = RB;
  conv(xcb, Wt5a, lvl[0], n2, tab[0], 336, 256, t5a);
  stats(t5a, n2, 256, g5a, b5a);
  unsigned short* t5ab = xcb;  // xcb free after conv5a
  cvt(t5a, t5ab, (long long)n2 * 256, 256);

  float* t5b = RG;
  conv(t5ab, Wt5b, lvl[1], n4, tab[1], 256, 512, t5b);
  stats(t5b, n4, 512, g5b, b5b);
  cvt(t5b, t5bb, (long long)n4 * 512, 512);

  float* outp = (float*)d_out;
  conv(t5bb, Wt5c, lvl[2], n8, tab[2], 512, 1024, outp);
  stats(outp, n8, 1024, g5c, b5c);
  long long total4 = (long long)n8 * 1024 / 4;
  k_bn_apply<<<(int)((total4 + 255) / 256), 256, 0, stream>>>(outp, total4, 1024, abuf);
}

// Round 4
// 1861.361 us; speedup vs baseline: 1.4004x; 1.0530x over previous
//
#include <hip/hip_runtime.h>
#include <cstdint>
#include <cstddef>

#define GDIM 512

typedef __attribute__((ext_vector_type(8))) short short8;
typedef __attribute__((ext_vector_type(4))) float f32x4;
typedef __attribute__((ext_vector_type(4))) unsigned short ushort4v;

__device__ __forceinline__ short f2bf(float f) {
  unsigned u = __float_as_uint(f);
  u = u + 0x7fffu + ((u >> 16) & 1u);  // round-to-nearest-even
  return (short)(u >> 16);
}

// ---------------------------------------------------------------- hash table
__device__ __forceinline__ int hash_lookup(int key, const int* __restrict__ keys,
                                           const int* __restrict__ vals, unsigned capmask) {
  unsigned slot = ((unsigned)key * 2654435761u) & capmask;
  while (true) {
    int kk = keys[slot];
    if (kk == key) return vals[slot];
    if (kk == -1) return -1;
    slot = (slot + 1) & capmask;
  }
}

__global__ void k_build_table(const int* __restrict__ coords, int n, int sh, int Gs,
                              int* __restrict__ keys, int* __restrict__ vals, unsigned capmask) {
  int i = blockIdx.x * blockDim.x + threadIdx.x;
  if (i >= n) return;
  int b = coords[4 * i];
  int key = ((b * Gs + (coords[4 * i + 1] >> sh)) * Gs + (coords[4 * i + 2] >> sh)) * Gs +
            (coords[4 * i + 3] >> sh);
  unsigned slot = ((unsigned)key * 2654435761u) & capmask;
  while (true) {
    int prev = atomicCAS(&keys[slot], -1, key);
    if (prev == -1) { vals[slot] = i; return; }
    slot = (slot + 1) & capmask;
  }
}

// ---------------------------------------------- conv: idxT (transposed query)
__global__ void k_query_idx_t(const int* __restrict__ oc, int m, int sh, int Gs,
                              const int* __restrict__ keys, const int* __restrict__ vals,
                              unsigned capmask, int* __restrict__ idxT) {
  int k = blockIdx.y;
  int o = blockIdx.x * blockDim.x + threadIdx.x;
  if (o >= m) return;
  int stride = 1 << sh;
  int dx = k / 9 - 1, dy = (k / 3) % 3 - 1, dz = k % 3 - 1;
  int4 c = *(const int4*)(oc + 4 * o);
  int qx = c.y + dx * stride;
  int qy = c.z + dy * stride;
  int qz = c.w + dz * stride;
  int res = -1;
  if ((unsigned)qx < GDIM && (unsigned)qy < GDIM && (unsigned)qz < GDIM) {
    int key = ((c.x * Gs + (qx >> sh)) * Gs + (qy >> sh)) * Gs + (qz >> sh);
    res = hash_lookup(key, keys, vals, capmask);
  }
  idxT[(size_t)k * m + o] = res;
}

// Split pairs into owner (first hit per output) and rest. Every output has
// >=1 hit (its own child cell), so owner GEMM plain-stores.
__global__ void k_make_pairs(const int* __restrict__ idxT, int m,
                             int* __restrict__ po_o, int* __restrict__ pi_o,
                             int* __restrict__ po_r, int* __restrict__ pi_r,
                             int* __restrict__ cnts, int mcap) {
  int o = blockIdx.x * blockDim.x + threadIdx.x;
  bool act = o < m;
  int lane = threadIdx.x & 63;
  bool owned = false;
  for (int k = 0; k < 27; ++k) {
    int i = act ? idxT[(size_t)k * m + o] : -1;
    bool hit = i >= 0;
    bool isown = hit && !owned;
    if (isown) owned = true;
    bool isrest = hit && !isown;
    unsigned long long bo = __ballot(isown);
    if (bo) {
      int ldr = __ffsll((unsigned long long)bo) - 1;
      int base = 0;
      if (lane == ldr) base = atomicAdd(&cnts[k], __popcll(bo));
      base = __shfl(base, ldr);
      if (isown) {
        int p = base + __popcll(bo & ((1ull << lane) - 1ull));
        po_o[k * mcap + p] = o;
        pi_o[k * mcap + p] = i;
      }
    }
    unsigned long long br = __ballot(isrest);
    if (br) {
      int ldr = __ffsll((unsigned long long)br) - 1;
      int base = 0;
      if (lane == ldr) base = atomicAdd(&cnts[27 + k], __popcll(br));
      base = __shfl(base, ldr);
      if (isrest) {
        int p = base + __popcll(br & ((1ull << lane) - 1ull));
        po_r[k * mcap + p] = o;
        pi_r[k * mcap + p] = i;
      }
    }
  }
}

// plan: exclusive prefix over cdiv(cnt_k, 64) for owner [0..27] and rest [28..55]
__global__ void k_plan(const int* __restrict__ cnts, int* __restrict__ plan) {
  if (threadIdx.x == 0) {
    int acc = 0;
    for (int k = 0; k < 27; ++k) { plan[k] = acc; acc += (cnts[k] + 63) >> 6; }
    plan[27] = acc;
    acc = 0;
    for (int k = 0; k < 27; ++k) { plan[28 + k] = acc; acc += (cnts[27 + k] + 63) >> 6; }
    plan[55] = acc;
  }
}

// --------------------------------------------- MFMA bf16 gather-GEMM-scatter
// Compacted work list: grid-stride over virtual block v in [0, NB); v -> (k,p0)
// via plan prefix. blockIdx.y = cout 128-tile. 64 pairs x 128 cout per unit.
template<bool OWNER>
__global__ __launch_bounds__(256) void k_conv_mfma(
    const unsigned short* __restrict__ Fb,  // bf16 [rows][cin]
    const short* __restrict__ Wt,           // bf16 [27][cout][cin]
    float* __restrict__ out,
    const int* __restrict__ plo, const int* __restrict__ pli,
    const int* __restrict__ counts, const int* __restrict__ plan,
    int cin, int cin_pad, int cout, int mcap) {
  __shared__ int pshared[28];
  __shared__ short Alds[64 * 136];      // 128-k slab + 8 pad
  __shared__ short Blds[2][128 * 40];   // 32-k slice + 8 pad, double-buffered
  __shared__ int rows_out[64];
  __shared__ int rows_in[64];

  int tid = threadIdx.x;
  if (tid < 28) pshared[tid] = plan[tid];
  __syncthreads();
  int NB = pshared[27];

  int n0 = blockIdx.y << 7;
  int wave = tid >> 6, lane = tid & 63;
  int wm = (wave & 1) * 32, wn = (wave >> 1) * 64;
  int lm = lane & 15, quad = lane >> 4;
  int bn0 = (tid) >> 2, bk0 = (tid & 3) << 3;
  int bn1 = (tid + 256) >> 2, bk1 = ((tid + 256) & 3) << 3;

  for (int v = blockIdx.x; v < NB; v += gridDim.x) {
    int k = 0;
    #pragma unroll
    for (int kk = 1; kk < 27; ++kk) k += (v >= pshared[kk]);
    int cnt = counts[k];
    int p0 = (v - pshared[k]) << 6;
    int np = min(64, cnt - p0);

    __syncthreads();  // prior v's readers of rows_*/Alds done
    if (tid < 64) {
      rows_out[tid] = (tid < np) ? plo[k * mcap + p0 + tid] : -1;
      rows_in [tid] = (tid < np) ? pli[k * mcap + p0 + tid] : -1;
    }
    const short* Wk = Wt + (size_t)k * cout * cin;
    f32x4 acc[2][4] = {};

    for (int ks = 0; ks < cin_pad; ks += 128) {
      int kslab = min(128, cin_pad - ks);
      int aStride = kslab + 8;
      __syncthreads();  // rows ready (ks==0); A readers of prev slab done
      int clog = kslab == 128 ? 4 : (kslab == 64 ? 3 : 2);
      for (int u = tid; u < (64 << clog); u += 256) {
        int r = u >> clog;
        int kc = (u - (r << clog)) << 3;
        int gk = ks + kc;
        int irow = rows_in[r];
        short8 v8 = {0, 0, 0, 0, 0, 0, 0, 0};
        if (irow >= 0 && gk < cin)
          v8 = *(const short8*)((const short*)Fb + (size_t)irow * cin + gk);
        *(short8*)(Alds + r * aStride + kc) = v8;
      }
      int nsl = kslab >> 5;
      short8 br0 = {0, 0, 0, 0, 0, 0, 0, 0}, br1 = br0;
      {
        int gn = n0 + bn0, gk = ks + bk0;
        if (gn < cout && gk < cin) br0 = *(const short8*)(Wk + (size_t)gn * cin + gk);
        gn = n0 + bn1; gk = ks + bk1;
        if (gn < cout && gk < cin) br1 = *(const short8*)(Wk + (size_t)gn * cin + gk);
      }
      for (int j = 0; j < nsl; ++j) {
        __syncthreads();  // A staged (j==0); Bbuf[j&1] readers (j-2) done
        *(short8*)(&Blds[j & 1][bn0 * 40 + bk0]) = br0;
        *(short8*)(&Blds[j & 1][bn1 * 40 + bk1]) = br1;
        if (j + 1 < nsl) {
          int gkbase = ks + (j + 1) * 32;
          short8 z = {0, 0, 0, 0, 0, 0, 0, 0};
          br0 = z; br1 = z;
          int gn = n0 + bn0, gk = gkbase + bk0;
          if (gn < cout && gk < cin) br0 = *(const short8*)(Wk + (size_t)gn * cin + gk);
          gn = n0 + bn1; gk = gkbase + bk1;
          if (gn < cout && gk < cin) br1 = *(const short8*)(Wk + (size_t)gn * cin + gk);
        }
        __syncthreads();  // B visible
        int ka = j * 32 + quad * 8;
        short8 a0 = *(const short8*)(Alds + (wm + lm) * aStride + ka);
        short8 a1 = *(const short8*)(Alds + (wm + 16 + lm) * aStride + ka);
        #pragma unroll
        for (int nt = 0; nt < 4; ++nt) {
          short8 b = *(const short8*)(&Blds[j & 1][(wn + nt * 16 + lm) * 40 + quad * 8]);
          acc[0][nt] = __builtin_amdgcn_mfma_f32_16x16x32_bf16(a0, b, acc[0][nt], 0, 0, 0);
          acc[1][nt] = __builtin_amdgcn_mfma_f32_16x16x32_bf16(a1, b, acc[1][nt], 0, 0, 0);
        }
      }
    }
    #pragma unroll
    for (int mt = 0; mt < 2; ++mt)
      #pragma unroll
      for (int nt = 0; nt < 4; ++nt)
        #pragma unroll
        for (int r = 0; r < 4; ++r) {
          int row = wm + mt * 16 + quad * 4 + r;
          int col = n0 + wn + nt * 16 + lm;
          if (row < np && col < cout) {
            if (OWNER)
              out[(size_t)rows_out[row] * cout + col] = acc[mt][nt][r];
            else
              atomicAdd(&out[(size_t)rows_out[row] * cout + col], acc[mt][nt][r]);
          }
        }
  }
}

// ------------------------------------------- weight convert+transpose to bf16
__global__ void k_convert_w(const float* __restrict__ W, short* __restrict__ Wt,
                            int cin, int cout) {
  __shared__ float tile[32][33];
  int k = blockIdx.z;
  int n0 = blockIdx.x * 32, c0 = blockIdx.y * 32;
  int tx = threadIdx.x & 31, ty = threadIdx.x >> 5;
  const float* Wk = W + (size_t)k * cin * cout;
  for (int i = ty; i < 32; i += 8) {
    int c = c0 + i, n = n0 + tx;
    tile[i][tx] = (c < cin && n < cout) ? Wk[(size_t)c * cout + n] : 0.f;
  }
  __syncthreads();
  short* Wtk = Wt + (size_t)k * cout * cin;
  for (int i = ty; i < 32; i += 8) {
    int n = n0 + i, c = c0 + tx;
    if (n < cout && c < cin) Wtk[(size_t)n * cin + c] = f2bf(tile[tx][i]);
  }
}

// ------------------------------------------------------------------ maxpool
__global__ void k_query_idx(const int* __restrict__ oc, int m, int sh, int Gs,
                            const int* __restrict__ keys, const int* __restrict__ vals,
                            unsigned capmask, int* __restrict__ idx) {
  int t = blockIdx.x * blockDim.x + threadIdx.x;
  if (t >= m * 27) return;
  int o = t / 27, k = t - o * 27;
  int stride = 1 << sh;
  int dx = k / 9 - 1, dy = (k / 3) % 3 - 1, dz = k % 3 - 1;
  int b  = oc[4 * o];
  int qx = oc[4 * o + 1] + dx * stride;
  int qy = oc[4 * o + 2] + dy * stride;
  int qz = oc[4 * o + 3] + dz * stride;
  int res = -1;
  if ((unsigned)qx < GDIM && (unsigned)qy < GDIM && (unsigned)qz < GDIM) {
    int key = ((b * Gs + (qx >> sh)) * Gs + (qy >> sh)) * Gs + (qz >> sh);
    res = hash_lookup(key, keys, vals, capmask);
  }
  idx[t] = res;
}

__global__ void k_maxpool_bn(const float* __restrict__ F, unsigned short* __restrict__ out,
                             const int* __restrict__ idx, int m, int C,
                             const float* __restrict__ ab) {
  long long t = (long long)blockIdx.x * blockDim.x + threadIdx.x;
  if (t >= (long long)m * C) return;
  int o = (int)(t / C), c = (int)(t - (long long)o * C);
  float a = ab[c], b = ab[C + c];
  float best = -3e38f;
  #pragma unroll 1
  for (int k = 0; k < 27; ++k) {
    int i = idx[o * 27 + k];
    if (i >= 0) {
      float y = a * F[(size_t)i * C + c] + b;
      y = fmaxf(y, 0.01f * y);
      best = fmaxf(best, y);
    }
  }
  out[t] = (unsigned short)f2bf(best);
}

// -------------------------------------------------------- slice / gather / mlp
__global__ void k_slice_idx(const int* __restrict__ coords, int n, int sh, int Gs,
                            const int* __restrict__ keys, const int* __restrict__ vals,
                            unsigned capmask, int* __restrict__ sidx) {
  int i = blockIdx.x * blockDim.x + threadIdx.x;
  if (i >= n) return;
  int b = coords[4 * i];
  int key = ((b * Gs + (coords[4 * i + 1] >> sh)) * Gs + (coords[4 * i + 2] >> sh)) * Gs +
            (coords[4 * i + 3] >> sh);
  int v = hash_lookup(key, keys, vals, capmask);
  sidx[i] = (v < 0) ? 0 : v;
}

__global__ void k_gather_cols16(const unsigned short* __restrict__ src, int C,
                                const int* __restrict__ sidx,
                                unsigned short* __restrict__ dst, int dstC, int colOff, int n) {
  long long t = (long long)blockIdx.x * blockDim.x + threadIdx.x;
  if (t >= (long long)n * C) return;
  int o = (int)(t / C), c = (int)(t - (long long)o * C);
  dst[(size_t)o * dstC + colOff + c] = src[(size_t)sidx[o] * C + c];
}

__global__ void k_mlp(const float* __restrict__ feats, const float* __restrict__ w,
                      float* __restrict__ x, int n) {
  int t = blockIdx.x * blockDim.x + threadIdx.x;
  if (t >= n * 32) return;
  x[t] = feats[t >> 5] * w[t & 31];
}

// ----------------------------------------------------------------------- BN
__global__ void k_bn_stats(const float* __restrict__ x, int m, int C,
                           float* __restrict__ sums) {
  __shared__ float ls[2][256];
  int tid = threadIdx.x;
  int RL = (C >= 256) ? 1 : (256 / C);
  int c, rl;
  bool active;
  if (C >= 256) { c = blockIdx.y * 256 + tid; rl = 0; active = true; }
  else { c = tid % C; rl = tid / C; active = (tid < RL * C); }
  float s = 0.f, s2 = 0.f;
  if (active) {
    int step = gridDim.x * RL;
    for (int r = blockIdx.x * RL + rl; r < m; r += step) {
      float v = x[(size_t)r * C + c];
      s += v; s2 += v * v;
    }
  }
  if (RL == 1) {
    atomicAdd(&sums[c], s);
    atomicAdd(&sums[C + c], s2);
  } else {
    ls[0][tid] = s; ls[1][tid] = s2;
    __syncthreads();
    if (tid < C) {
      for (int j = 1; j < RL; ++j) { s += ls[0][c + j * C]; s2 += ls[1][c + j * C]; }
      atomicAdd(&sums[c], s);
      atomicAdd(&sums[C + c], s2);
    }
  }
}

__global__ void k_bn_finalize(const float* __restrict__ sums, const float* __restrict__ gamma,
                              const float* __restrict__ beta, int C, float inv_m,
                              float* __restrict__ ab) {
  for (int c = threadIdx.x; c < C; c += 256) {
    float mu  = sums[c] * inv_m;
    float var = sums[C + c] * inv_m - mu * mu;
    float a = rsqrtf(var + 1e-5f) * gamma[c];
    ab[c] = a;
    ab[C + c] = beta[c] - mu * a;
  }
}

// fused bn+lrelu -> bf16, float4/ushort4 vectorized (C % 4 == 0)
__global__ void k_bn_bf16(const float* __restrict__ x, unsigned short* __restrict__ xb,
                          long long total4, int C, const float* __restrict__ ab) {
  long long t = (long long)blockIdx.x * blockDim.x + threadIdx.x;
  if (t >= total4) return;
  long long e = t * 4;
  int c = (int)(e % C);
  float4 v = *(const float4*)(x + e);
  ushort4v o;
  float y0 = ab[c] * v.x + ab[C + c];         o.x = (unsigned short)f2bf(fmaxf(y0, 0.01f * y0));
  float y1 = ab[c + 1] * v.y + ab[C + c + 1]; o.y = (unsigned short)f2bf(fmaxf(y1, 0.01f * y1));
  float y2 = ab[c + 2] * v.z + ab[C + c + 2]; o.z = (unsigned short)f2bf(fmaxf(y2, 0.01f * y2));
  float y3 = ab[c + 3] * v.w + ab[C + c + 3]; o.w = (unsigned short)f2bf(fmaxf(y3, 0.01f * y3));
  *(ushort4v*)(xb + e) = o;
}

__global__ void k_bn_apply(float* __restrict__ x, long long total4, int C,
                           const float* __restrict__ ab) {
  long long t = (long long)blockIdx.x * blockDim.x + threadIdx.x;
  if (t >= total4) return;
  long long e = t * 4;
  int c = (int)(e % C);
  float4 v = *(const float4*)(x + e);
  float y0 = ab[c] * v.x + ab[C + c];         v.x = fmaxf(y0, 0.01f * y0);
  float y1 = ab[c + 1] * v.y + ab[C + c + 1]; v.y = fmaxf(y1, 0.01f * y1);
  float y2 = ab[c + 2] * v.z + ab[C + c + 2]; v.z = fmaxf(y2, 0.01f * y2);
  float y3 = ab[c + 3] * v.w + ab[C + c + 3]; v.w = fmaxf(y3, 0.01f * y3);
  *(float4*)(x + e) = v;
}

// ---------------------------------------------------------------------- host
static inline int cdiv(int a, int b) { return (a + b - 1) / b; }

extern "C" void kernel_launch(void* const* d_in, const int* in_sizes, int n_in,
                              void* d_out, int out_size, void* d_ws, size_t ws_size,
                              hipStream_t stream) {
  (void)n_in; (void)out_size; (void)ws_size;
  const float* feats  = (const float*)d_in[0];
  const int*   coords = (const int*)d_in[1];
  const float* w_mlp = (const float*)d_in[2];
  const float* gm  = (const float*)d_in[3];  const float* bm  = (const float*)d_in[4];
  const float* W1  = (const float*)d_in[5];  const float* g1  = (const float*)d_in[6];  const float* b1  = (const float*)d_in[7];
  const float* W2  = (const float*)d_in[8];  const float* g2  = (const float*)d_in[9];  const float* b2  = (const float*)d_in[10];
  const float* W3  = (const float*)d_in[11]; const float* g3  = (const float*)d_in[12]; const float* b3  = (const float*)d_in[13];
  const float* W4  = (const float*)d_in[14]; const float* g4  = (const float*)d_in[15]; const float* b4  = (const float*)d_in[16];
  const float* W5a = (const float*)d_in[17]; const float* g5a = (const float*)d_in[18]; const float* b5a = (const float*)d_in[19];
  const float* W5b = (const float*)d_in[20]; const float* g5b = (const float*)d_in[21]; const float* b5b = (const float*)d_in[22];
  const float* W5c = (const float*)d_in[23]; const float* g5c = (const float*)d_in[24]; const float* b5c = (const float*)d_in[25];
  const int*   lvl[7];
  for (int i = 0; i < 7; ++i) lvl[i] = (const int*)d_in[26 + i];

  const int N = in_sizes[0];
  int nl[7];
  for (int i = 0; i < 7; ++i) nl[i] = in_sizes[26 + i] / 4;
  const int n2 = nl[0], n4 = nl[1], n8 = nl[2], n16 = nl[3], n32 = nl[4], n64 = nl[5], n128 = nl[6];

  char* ws = (char*)d_ws;
  size_t off = 0;
  auto alloc = [&](size_t bytes) -> char* {
    off = (off + 255) & ~(size_t)255;
    char* p = ws + off;
    off += bytes;
    return p;
  };

  struct Tab { int* keys; int* vals; unsigned mask; int sh; int Gs; int n; const int* src; };
  Tab tab[8];
  const int* tsrc[8] = {coords, lvl[0], lvl[1], lvl[2], lvl[3], lvl[4], lvl[5], lvl[6]};
  int tn[8] = {N, n2, n4, n8, n16, n32, n64, n128};
  for (int i = 0; i < 8; ++i) {
    int cap = 64;
    while (cap < 2 * tn[i]) cap <<= 1;
    tab[i].keys = (int*)alloc((size_t)cap * 4);
    tab[i].vals = (int*)alloc((size_t)cap * 4);
    tab[i].mask = (unsigned)(cap - 1);
    tab[i].sh = i;
    tab[i].Gs = GDIM >> i;
    tab[i].n = tn[i];
    tab[i].src = tsrc[i];
  }

  int* pout   = (int*)alloc((size_t)27 * N * 4);   // owner lists
  int* pin    = (int*)alloc((size_t)27 * N * 4);
  int* pout_r = (int*)alloc((size_t)27 * N * 4);   // rest lists
  int* pin_r  = (int*)alloc((size_t)27 * N * 4);
  int* counts = (int*)alloc(256);                  // [0..26] owner, [27..53] rest
  int* plan   = (int*)alloc(256);                  // [0..27] owner bstart, [28..55] rest
  int* idxbuf = (int*)alloc((size_t)27 * N * 4);
  int* sidx[4];
  for (int i = 0; i < 4; ++i) sidx[i] = (int*)alloc((size_t)N * 4);
  float* bnsum = (float*)alloc(2 * 1024 * 4);
  float* abuf  = (float*)alloc(2 * 1024 * 4);

  auto mxz = [](size_t a, size_t b) { return a > b ? a : b; };
  size_t szA = mxz(mxz((size_t)N * 32, (size_t)n4 * 64), (size_t)n64 * 128) * 4;
  size_t szB = mxz(mxz((size_t)N * 48, (size_t)n16 * 96), (size_t)n2 * 256) * 4;
  float* RA = (float*)alloc(szA);
  float* RB = (float*)alloc(szB);
  float* RG = (float*)alloc((size_t)n4 * 512 * 4);                                 // t5b
  unsigned short* xb  = (unsigned short*)alloc((size_t)N * 32 * 2);
  unsigned short* y1b = (unsigned short*)alloc((size_t)n2 * 48 * 2);
  unsigned short* y2b = (unsigned short*)alloc((size_t)n8 * 64 * 2);
  unsigned short* y3b = (unsigned short*)alloc((size_t)n32 * 96 * 2);
  unsigned short* y4b = (unsigned short*)alloc((size_t)n128 * 128 * 2);
  unsigned short* xcb = (unsigned short*)alloc((size_t)N * 336 * 2);
  unsigned short* t5bb = (unsigned short*)alloc((size_t)n4 * 512 * 2);
  short* Wt1  = (short*)alloc((size_t)27 * 32 * 48 * 2);
  short* Wt2  = (short*)alloc((size_t)27 * 48 * 64 * 2);
  short* Wt3  = (short*)alloc((size_t)27 * 64 * 96 * 2);
  short* Wt4  = (short*)alloc((size_t)27 * 96 * 128 * 2);
  short* Wt5a = (short*)alloc((size_t)27 * 336 * 256 * 2);
  short* Wt5b = (short*)alloc((size_t)27 * 256 * 512 * 2);
  short* Wt5c = (short*)alloc((size_t)27 * 512 * 1024 * 2);

  // hash tables
  for (int i = 0; i < 8; ++i)
    hipMemsetAsync(tab[i].keys, 0xFF, (size_t)(tab[i].mask + 1) * 4, stream);
  for (int i = 0; i < 8; ++i)
    k_build_table<<<cdiv(tab[i].n, 256), 256, 0, stream>>>(
        tab[i].src, tab[i].n, tab[i].sh, tab[i].Gs, tab[i].keys, tab[i].vals, tab[i].mask);

  auto convW = [&](const float* W, short* Wt, int cin, int cout) {
    dim3 g(cdiv(cout, 32), cdiv(cin, 32), 27);
    k_convert_w<<<g, 256, 0, stream>>>(W, Wt, cin, cout);
  };
  convW(W1, Wt1, 32, 48);     convW(W2, Wt2, 48, 64);
  convW(W3, Wt3, 64, 96);     convW(W4, Wt4, 96, 128);
  convW(W5a, Wt5a, 336, 256); convW(W5b, Wt5b, 256, 512);
  convW(W5c, Wt5c, 512, 1024);

  auto conv = [&](const unsigned short* Fb, const short* Wt, const int* oc, int m,
                  const Tab& t, int cin, int cout, float* out) {
    hipMemsetAsync(counts, 0, 54 * 4, stream);
    dim3 gq(cdiv(m, 256), 27);
    k_query_idx_t<<<gq, 256, 0, stream>>>(oc, m, t.sh, t.Gs, t.keys, t.vals, t.mask, idxbuf);
    k_make_pairs<<<cdiv(m, 256), 256, 0, stream>>>(idxbuf, m, pout, pin, pout_r, pin_r,
                                                   counts, N);
    k_plan<<<1, 64, 0, stream>>>(counts, plan);
    int cin_pad = cin <= 32 ? 32 : (cin <= 64 ? 64 : ((cin + 127) & ~127));
    int nT = cdiv(cout, 128);
    int G = cdiv(m, 64) + 27;
    if (G > 2048) G = 2048;
    dim3 gridc(G, nT);
    k_conv_mfma<true><<<gridc, 256, 0, stream>>>(Fb, Wt, out, pout, pin, counts, plan,
                                                 cin, cin_pad, cout, N);
    k_conv_mfma<false><<<gridc, 256, 0, stream>>>(Fb, Wt, out, pout_r, pin_r, counts + 27,
                                                  plan + 28, cin, cin_pad, cout, N);
  };
  auto stats = [&](const float* x, int m, int C, const float* gamma, const float* beta) {
    hipMemsetAsync(bnsum, 0, (size_t)2 * C * 4, stream);
    int CG = (C >= 256) ? (C / 256) : 1;
    int RL = (C >= 256) ? 1 : (256 / C);
    int NS = (C >= 256) ? 512 : 256;
    int maxNS = cdiv(m, RL);
    if (NS > maxNS) NS = maxNS < 1 ? 1 : maxNS;
    dim3 g(NS, CG);
    k_bn_stats<<<g, 256, 0, stream>>>(x, m, C, bnsum);
    k_bn_finalize<<<1, 256, 0, stream>>>(bnsum, gamma, beta, C, 1.0f / (float)m, abuf);
  };
  auto pool = [&](const float* F, const int* oc, int m, const Tab& t, int C,
                  unsigned short* out) {
    k_query_idx<<<cdiv(m * 27, 256), 256, 0, stream>>>(
        oc, m, t.sh, t.Gs, t.keys, t.vals, t.mask, idxbuf);
    long long total = (long long)m * C;
    k_maxpool_bn<<<(int)((total + 255) / 256), 256, 0, stream>>>(F, out, idxbuf, m, C, abuf);
  };
  auto cvt = [&](const float* src, unsigned short* dst, long long total, int C) {
    long long t4 = total / 4;
    k_bn_bf16<<<(int)((t4 + 255) / 256), 256, 0, stream>>>(src, dst, t4, C, abuf);
  };

  // ---- network ----
  float* x = RA;
  k_mlp<<<cdiv(N * 32, 256), 256, 0, stream>>>(feats, w_mlp, x, N);
  stats(x, N, 32, gm, bm);
  cvt(x, xb, (long long)N * 32, 32);                    // bn(mlp)+lrelu -> bf16

  float* t1 = RB;
  conv(xb, Wt1, coords, N, tab[0], 32, 48, t1);
  stats(t1, N, 48, g1, b1);
  pool(t1, lvl[0], n2, tab[0], 48, y1b);

  float* t2 = RA;
  conv(y1b, Wt2, lvl[1], n4, tab[1], 48, 64, t2);
  stats(t2, n4, 64, g2, b2);
  pool(t2, lvl[2], n8, tab[2], 64, y2b);

  float* t3 = RB;
  conv(y2b, Wt3, lvl[3], n16, tab[3], 64, 96, t3);
  stats(t3, n16, 96, g3, b3);
  pool(t3, lvl[4], n32, tab[4], 96, y3b);

  float* t4 = RA;
  conv(y3b, Wt4, lvl[5], n64, tab[5], 96, 128, t4);
  stats(t4, n64, 128, g4, b4);
  pool(t4, lvl[6], n128, tab[6], 128, y4b);

  // slice_to_field -> xcb (bf16)
  k_slice_idx<<<cdiv(N, 256), 256, 0, stream>>>(coords, N, tab[1].sh, tab[1].Gs,
                                                tab[1].keys, tab[1].vals, tab[1].mask, sidx[0]);
  k_slice_idx<<<cdiv(N, 256), 256, 0, stream>>>(coords, N, tab[3].sh, tab[3].Gs,
                                                tab[3].keys, tab[3].vals, tab[3].mask, sidx[1]);
  k_slice_idx<<<cdiv(N, 256), 256, 0, stream>>>(coords, N, tab[5].sh, tab[5].Gs,
                                                tab[5].keys, tab[5].vals, tab[5].mask, sidx[2]);
  k_slice_idx<<<cdiv(N, 256), 256, 0, stream>>>(coords, N, tab[7].sh, tab[7].Gs,
                                                tab[7].keys, tab[7].vals, tab[7].mask, sidx[3]);
  k_gather_cols16<<<(int)(((long long)N * 48 + 255) / 256), 256, 0, stream>>>(y1b, 48, sidx[0], xcb, 336, 0, N);
  k_gather_cols16<<<(int)(((long long)N * 64 + 255) / 256), 256, 0, stream>>>(y2b, 64, sidx[1], xcb, 336, 48, N);
  k_gather_cols16<<<(int)(((long long)N * 96 + 255) / 256), 256, 0, stream>>>(y3b, 96, sidx[2], xcb, 336, 112, N);
  k_gather_cols16<<<(int)(((long long)N * 128 + 255) / 256), 256, 0, stream>>>(y4b, 128, sidx[3], xcb, 336, 208, N);

  float* t5a = RB;
  conv(xcb, Wt5a, lvl[0], n2, tab[0], 336, 256, t5a);
  stats(t5a, n2, 256, g5a, b5a);
  unsigned short* t5ab = xcb;  // xcb free after conv5a
  cvt(t5a, t5ab, (long long)n2 * 256, 256);

  float* t5b = RG;
  conv(t5ab, Wt5b, lvl[1], n4, tab[1], 256, 512, t5b);
  stats(t5b, n4, 512, g5b, b5b);
  cvt(t5b, t5bb, (long long)n4 * 512, 512);

  float* outp = (float*)d_out;
  conv(t5bb, Wt5c, lvl[2], n8, tab[2], 512, 1024, outp);
  stats(outp, n8, 1024, g5c, b5c);
  long long total4 = (long long)n8 * 1024 / 4;
  k_bn_apply<<<(int)((total4 + 255) / 256), 256, 0, stream>>>(outp, total4, 1024, abuf);
}

// Round 5
// 1820.111 us; speedup vs baseline: 1.4321x; 1.0227x over previous
//
#include <hip/hip_runtime.h>
#include <cstdint>
#include <cstddef>

#define GDIM 512

typedef __attribute__((ext_vector_type(8))) short short8;
typedef __attribute__((ext_vector_type(4))) float f32x4;
typedef __attribute__((ext_vector_type(4))) unsigned short ushort4v;

__device__ __forceinline__ short f2bf(float f) {
  unsigned u = __float_as_uint(f);
  u = u + 0x7fffu + ((u >> 16) & 1u);  // round-to-nearest-even
  return (short)(u >> 16);
}

// ---------------------------------------------------------------- hash table
__device__ __forceinline__ int hash_lookup(int key, const int* __restrict__ keys,
                                           const int* __restrict__ vals, unsigned capmask) {
  unsigned slot = ((unsigned)key * 2654435761u) & capmask;
  while (true) {
    int kk = keys[slot];
    if (kk == key) return vals[slot];
    if (kk == -1) return -1;
    slot = (slot + 1) & capmask;
  }
}

__global__ void k_build_table(const int* __restrict__ coords, int n, int sh, int Gs,
                              int* __restrict__ keys, int* __restrict__ vals, unsigned capmask) {
  int i = blockIdx.x * blockDim.x + threadIdx.x;
  if (i >= n) return;
  int b = coords[4 * i];
  int key = ((b * Gs + (coords[4 * i + 1] >> sh)) * Gs + (coords[4 * i + 2] >> sh)) * Gs +
            (coords[4 * i + 3] >> sh);
  unsigned slot = ((unsigned)key * 2654435761u) & capmask;
  while (true) {
    int prev = atomicCAS(&keys[slot], -1, key);
    if (prev == -1) { vals[slot] = i; return; }
    slot = (slot + 1) & capmask;
  }
}

// ---------------------------------------------- conv: idxT (transposed query)
__global__ void k_query_idx_t(const int* __restrict__ oc, int m, int sh, int Gs,
                              const int* __restrict__ keys, const int* __restrict__ vals,
                              unsigned capmask, int* __restrict__ idxT) {
  int k = blockIdx.y;
  int o = blockIdx.x * blockDim.x + threadIdx.x;
  if (o >= m) return;
  int stride = 1 << sh;
  int dx = k / 9 - 1, dy = (k / 3) % 3 - 1, dz = k % 3 - 1;
  int4 c = *(const int4*)(oc + 4 * o);
  int qx = c.y + dx * stride;
  int qy = c.z + dy * stride;
  int qz = c.w + dz * stride;
  int res = -1;
  if ((unsigned)qx < GDIM && (unsigned)qy < GDIM && (unsigned)qz < GDIM) {
    int key = ((c.x * Gs + (qx >> sh)) * Gs + (qy >> sh)) * Gs + (qz >> sh);
    res = hash_lookup(key, keys, vals, capmask);
  }
  idxT[(size_t)k * m + o] = res;
}

// Split pairs into owner (first hit per output) and rest. Every output has
// >=1 hit (its own child cell), so owner GEMM plain-stores.
__global__ void k_make_pairs(const int* __restrict__ idxT, int m,
                             int* __restrict__ po_o, int* __restrict__ pi_o,
                             int* __restrict__ po_r, int* __restrict__ pi_r,
                             int* __restrict__ cnts, int mcap) {
  int o = blockIdx.x * blockDim.x + threadIdx.x;
  bool act = o < m;
  int lane = threadIdx.x & 63;
  bool owned = false;
  for (int k = 0; k < 27; ++k) {
    int i = act ? idxT[(size_t)k * m + o] : -1;
    bool hit = i >= 0;
    bool isown = hit && !owned;
    if (isown) owned = true;
    bool isrest = hit && !isown;
    unsigned long long bo = __ballot(isown);
    if (bo) {
      int ldr = __ffsll((unsigned long long)bo) - 1;
      int base = 0;
      if (lane == ldr) base = atomicAdd(&cnts[k], __popcll(bo));
      base = __shfl(base, ldr);
      if (isown) {
        int p = base + __popcll(bo & ((1ull << lane) - 1ull));
        po_o[k * mcap + p] = o;
        pi_o[k * mcap + p] = i;
      }
    }
    unsigned long long br = __ballot(isrest);
    if (br) {
      int ldr = __ffsll((unsigned long long)br) - 1;
      int base = 0;
      if (lane == ldr) base = atomicAdd(&cnts[27 + k], __popcll(br));
      base = __shfl(base, ldr);
      if (isrest) {
        int p = base + __popcll(br & ((1ull << lane) - 1ull));
        po_r[k * mcap + p] = o;
        pi_r[k * mcap + p] = i;
      }
    }
  }
}

// plan: exclusive prefix over cdiv(cnt_k, 128) for owner [0..27] and rest [28..55]
__global__ void k_plan(const int* __restrict__ cnts, int* __restrict__ plan) {
  if (threadIdx.x == 0) {
    int acc = 0;
    for (int k = 0; k < 27; ++k) { plan[k] = acc; acc += (cnts[k] + 127) >> 7; }
    plan[27] = acc;
    acc = 0;
    for (int k = 0; k < 27; ++k) { plan[28 + k] = acc; acc += (cnts[27 + k] + 127) >> 7; }
    plan[55] = acc;
  }
}

// --------------------------------------------- MFMA bf16 gather-GEMM-scatter
// Block tile 128 pairs x 128 cout, 4 waves each 64x64 (4x4 MFMA 16x16x32),
// A-slab K=64 in LDS, B 32-K slices double-buffered with register prefetch.
// blockIdx.x = cout tile (fast dim -> A-tile L2 reuse across cout tiles),
// blockIdx.y grid-strides the compacted (k, p0) work list.
template<bool OWNER>
__global__ __launch_bounds__(256) void k_conv_mfma(
    const unsigned short* __restrict__ Fb,  // bf16 [rows][cin]
    const short* __restrict__ Wt,           // bf16 [27][cout][cin]
    float* __restrict__ out,
    const int* __restrict__ plo, const int* __restrict__ pli,
    const int* __restrict__ counts, const int* __restrict__ plan,
    int cin, int cin_pad, int cout, int mcap) {
  __shared__ int pshared[28];
  __shared__ short Alds[128 * 72];      // 64-K slab + 8 pad
  __shared__ short Blds[2][128 * 40];   // 32-K slice + 8 pad, double-buffered
  __shared__ int rows_out[128];
  __shared__ int rows_in[128];

  int tid = threadIdx.x;
  if (tid < 28) pshared[tid] = plan[tid];
  __syncthreads();
  int NB = pshared[27];

  int n0 = blockIdx.x << 7;
  int wave = tid >> 6, lane = tid & 63;
  int wm = (wave & 1) * 64, wn = (wave >> 1) * 64;
  int lm = lane & 15, quad = lane >> 4;
  int bn0 = tid >> 2, bk0 = (tid & 3) << 3;
  int bn1 = (tid + 256) >> 2, bk1 = ((tid + 256) & 3) << 3;
  int S = cin_pad >> 5;

  for (int v = blockIdx.y; v < NB; v += gridDim.y) {
    int k = 0;
    #pragma unroll
    for (int kk = 1; kk < 27; ++kk) k += (v >= pshared[kk]);
    int cnt = counts[k];
    int p0 = (v - pshared[k]) << 7;
    int np = min(128, cnt - p0);

    __syncthreads();  // prior v's epilogue reads of rows_out done
    if (tid < 128) {
      rows_out[tid] = (tid < np) ? plo[k * mcap + p0 + tid] : -1;
      rows_in [tid] = (tid < np) ? pli[k * mcap + p0 + tid] : -1;
    }
    const short* Wk = Wt + (size_t)k * cout * cin;
    f32x4 acc[4][4] = {};

    short8 br0 = {0, 0, 0, 0, 0, 0, 0, 0}, br1 = br0;  // prefetch B slice 0
    {
      int gn = n0 + bn0;
      if (gn < cout && bk0 < cin) br0 = *(const short8*)(Wk + (size_t)gn * cin + bk0);
      gn = n0 + bn1;
      if (gn < cout && bk1 < cin) br1 = *(const short8*)(Wk + (size_t)gn * cin + bk1);
    }
    for (int s = 0; s < S; ++s) {
      int ks = s << 5;
      __syncthreads();  // Blds[s&1] readers (s-2) done; Alds readers done; rows ready (s==0)
      if ((s & 1) == 0) {  // stage 64-wide A slab (or 32 tail)
        int kslab = min(64, cin_pad - ks);
        int clog = (kslab == 64) ? 3 : 2;
        for (int u = tid; u < (128 << clog); u += 256) {
          int r = u >> clog;
          int kc = (u - (r << clog)) << 3;
          int gk = ks + kc;
          int irow = rows_in[r];
          short8 v8 = {0, 0, 0, 0, 0, 0, 0, 0};
          if (irow >= 0 && gk < cin)
            v8 = *(const short8*)((const short*)Fb + (size_t)irow * cin + gk);
          *(short8*)(Alds + r * 72 + kc) = v8;
        }
      }
      *(short8*)(&Blds[s & 1][bn0 * 40 + bk0]) = br0;
      *(short8*)(&Blds[s & 1][bn1 * 40 + bk1]) = br1;
      if (s + 1 < S) {  // issue next-slice B loads; latency hides under MFMA
        int gkb = (s + 1) << 5;
        short8 z = {0, 0, 0, 0, 0, 0, 0, 0};
        br0 = z; br1 = z;
        int gn = n0 + bn0, gk = gkb + bk0;
        if (gn < cout && gk < cin) br0 = *(const short8*)(Wk + (size_t)gn * cin + gk);
        gn = n0 + bn1; gk = gkb + bk1;
        if (gn < cout && gk < cin) br1 = *(const short8*)(Wk + (size_t)gn * cin + gk);
      }
      __syncthreads();  // A slab + B slice visible
      int ka = ((s & 1) << 5) + quad * 8;
      short8 a[4], b[4];
      #pragma unroll
      for (int mt = 0; mt < 4; ++mt)
        a[mt] = *(const short8*)(Alds + (wm + mt * 16 + lm) * 72 + ka);
      #pragma unroll
      for (int nt = 0; nt < 4; ++nt)
        b[nt] = *(const short8*)(&Blds[s & 1][(wn + nt * 16 + lm) * 40 + quad * 8]);
      #pragma unroll
      for (int mt = 0; mt < 4; ++mt)
        #pragma unroll
        for (int nt = 0; nt < 4; ++nt)
          acc[mt][nt] = __builtin_amdgcn_mfma_f32_16x16x32_bf16(a[mt], b[nt], acc[mt][nt], 0, 0, 0);
    }
    #pragma unroll
    for (int mt = 0; mt < 4; ++mt)
      #pragma unroll
      for (int nt = 0; nt < 4; ++nt)
        #pragma unroll
        for (int r = 0; r < 4; ++r) {
          int row = wm + mt * 16 + quad * 4 + r;
          int col = n0 + wn + nt * 16 + lm;
          if (row < np && col < cout) {
            if (OWNER)
              out[(size_t)rows_out[row] * cout + col] = acc[mt][nt][r];
            else
              atomicAdd(&out[(size_t)rows_out[row] * cout + col], acc[mt][nt][r]);
          }
        }
  }
}

// ------------------------------------------- weight convert+transpose to bf16
__global__ void k_convert_w(const float* __restrict__ W, short* __restrict__ Wt,
                            int cin, int cout) {
  __shared__ float tile[32][33];
  int k = blockIdx.z;
  int n0 = blockIdx.x * 32, c0 = blockIdx.y * 32;
  int tx = threadIdx.x & 31, ty = threadIdx.x >> 5;
  const float* Wk = W + (size_t)k * cin * cout;
  for (int i = ty; i < 32; i += 8) {
    int c = c0 + i, n = n0 + tx;
    tile[i][tx] = (c < cin && n < cout) ? Wk[(size_t)c * cout + n] : 0.f;
  }
  __syncthreads();
  short* Wtk = Wt + (size_t)k * cout * cin;
  for (int i = ty; i < 32; i += 8) {
    int n = n0 + i, c = c0 + tx;
    if (n < cout && c < cin) Wtk[(size_t)n * cin + c] = f2bf(tile[tx][i]);
  }
}

// ------------------------------------------------------------------ maxpool
__global__ void k_query_idx(const int* __restrict__ oc, int m, int sh, int Gs,
                            const int* __restrict__ keys, const int* __restrict__ vals,
                            unsigned capmask, int* __restrict__ idx) {
  int t = blockIdx.x * blockDim.x + threadIdx.x;
  if (t >= m * 27) return;
  int o = t / 27, k = t - o * 27;
  int stride = 1 << sh;
  int dx = k / 9 - 1, dy = (k / 3) % 3 - 1, dz = k % 3 - 1;
  int b  = oc[4 * o];
  int qx = oc[4 * o + 1] + dx * stride;
  int qy = oc[4 * o + 2] + dy * stride;
  int qz = oc[4 * o + 3] + dz * stride;
  int res = -1;
  if ((unsigned)qx < GDIM && (unsigned)qy < GDIM && (unsigned)qz < GDIM) {
    int key = ((b * Gs + (qx >> sh)) * Gs + (qy >> sh)) * Gs + (qz >> sh);
    res = hash_lookup(key, keys, vals, capmask);
  }
  idx[t] = res;
}

__global__ void k_maxpool_bn(const float* __restrict__ F, unsigned short* __restrict__ out,
                             const int* __restrict__ idx, int m, int C,
                             const float* __restrict__ ab) {
  long long t = (long long)blockIdx.x * blockDim.x + threadIdx.x;
  if (t >= (long long)m * C) return;
  int o = (int)(t / C), c = (int)(t - (long long)o * C);
  float a = ab[c], b = ab[C + c];
  float best = -3e38f;
  #pragma unroll 1
  for (int k = 0; k < 27; ++k) {
    int i = idx[o * 27 + k];
    if (i >= 0) {
      float y = a * F[(size_t)i * C + c] + b;
      y = fmaxf(y, 0.01f * y);
      best = fmaxf(best, y);
    }
  }
  out[t] = (unsigned short)f2bf(best);
}

// -------------------------------------------------------- slice / gather / mlp
__global__ void k_slice_idx(const int* __restrict__ coords, int n, int sh, int Gs,
                            const int* __restrict__ keys, const int* __restrict__ vals,
                            unsigned capmask, int* __restrict__ sidx) {
  int i = blockIdx.x * blockDim.x + threadIdx.x;
  if (i >= n) return;
  int b = coords[4 * i];
  int key = ((b * Gs + (coords[4 * i + 1] >> sh)) * Gs + (coords[4 * i + 2] >> sh)) * Gs +
            (coords[4 * i + 3] >> sh);
  int v = hash_lookup(key, keys, vals, capmask);
  sidx[i] = (v < 0) ? 0 : v;
}

__global__ void k_gather_cols16(const unsigned short* __restrict__ src, int C,
                                const int* __restrict__ sidx,
                                unsigned short* __restrict__ dst, int dstC, int colOff, int n) {
  long long t = (long long)blockIdx.x * blockDim.x + threadIdx.x;
  if (t >= (long long)n * C) return;
  int o = (int)(t / C), c = (int)(t - (long long)o * C);
  dst[(size_t)o * dstC + colOff + c] = src[(size_t)sidx[o] * C + c];
}

__global__ void k_mlp(const float* __restrict__ feats, const float* __restrict__ w,
                      float* __restrict__ x, int n) {
  int t = blockIdx.x * blockDim.x + threadIdx.x;
  if (t >= n * 32) return;
  x[t] = feats[t >> 5] * w[t & 31];
}

// ----------------------------------------------------------------------- BN
__global__ void k_bn_stats(const float* __restrict__ x, int m, int C,
                           float* __restrict__ sums) {
  __shared__ float ls[2][256];
  int tid = threadIdx.x;
  int RL = (C >= 256) ? 1 : (256 / C);
  int c, rl;
  bool active;
  if (C >= 256) { c = blockIdx.y * 256 + tid; rl = 0; active = true; }
  else { c = tid % C; rl = tid / C; active = (tid < RL * C); }
  float s = 0.f, s2 = 0.f;
  if (active) {
    int step = gridDim.x * RL;
    for (int r = blockIdx.x * RL + rl; r < m; r += step) {
      float v = x[(size_t)r * C + c];
      s += v; s2 += v * v;
    }
  }
  if (RL == 1) {
    atomicAdd(&sums[c], s);
    atomicAdd(&sums[C + c], s2);
  } else {
    ls[0][tid] = s; ls[1][tid] = s2;
    __syncthreads();
    if (tid < C) {
      for (int j = 1; j < RL; ++j) { s += ls[0][c + j * C]; s2 += ls[1][c + j * C]; }
      atomicAdd(&sums[c], s);
      atomicAdd(&sums[C + c], s2);
    }
  }
}

__global__ void k_bn_finalize(const float* __restrict__ sums, const float* __restrict__ gamma,
                              const float* __restrict__ beta, int C, float inv_m,
                              float* __restrict__ ab) {
  for (int c = threadIdx.x; c < C; c += 256) {
    float mu  = sums[c] * inv_m;
    float var = sums[C + c] * inv_m - mu * mu;
    float a = rsqrtf(var + 1e-5f) * gamma[c];
    ab[c] = a;
    ab[C + c] = beta[c] - mu * a;
  }
}

// fused bn+lrelu -> bf16, float4/ushort4 vectorized (C % 4 == 0)
__global__ void k_bn_bf16(const float* __restrict__ x, unsigned short* __restrict__ xb,
                          long long total4, int C, const float* __restrict__ ab) {
  long long t = (long long)blockIdx.x * blockDim.x + threadIdx.x;
  if (t >= total4) return;
  long long e = t * 4;
  int c = (int)(e % C);
  float4 v = *(const float4*)(x + e);
  ushort4v o;
  float y0 = ab[c] * v.x + ab[C + c];         o.x = (unsigned short)f2bf(fmaxf(y0, 0.01f * y0));
  float y1 = ab[c + 1] * v.y + ab[C + c + 1]; o.y = (unsigned short)f2bf(fmaxf(y1, 0.01f * y1));
  float y2 = ab[c + 2] * v.z + ab[C + c + 2]; o.z = (unsigned short)f2bf(fmaxf(y2, 0.01f * y2));
  float y3 = ab[c + 3] * v.w + ab[C + c + 3]; o.w = (unsigned short)f2bf(fmaxf(y3, 0.01f * y3));
  *(ushort4v*)(xb + e) = o;
}

__global__ void k_bn_apply(float* __restrict__ x, long long total4, int C,
                           const float* __restrict__ ab) {
  long long t = (long long)blockIdx.x * blockDim.x + threadIdx.x;
  if (t >= total4) return;
  long long e = t * 4;
  int c = (int)(e % C);
  float4 v = *(const float4*)(x + e);
  float y0 = ab[c] * v.x + ab[C + c];         v.x = fmaxf(y0, 0.01f * y0);
  float y1 = ab[c + 1] * v.y + ab[C + c + 1]; v.y = fmaxf(y1, 0.01f * y1);
  float y2 = ab[c + 2] * v.z + ab[C + c + 2]; v.z = fmaxf(y2, 0.01f * y2);
  float y3 = ab[c + 3] * v.w + ab[C + c + 3]; v.w = fmaxf(y3, 0.01f * y3);
  *(float4*)(x + e) = v;
}

// ---------------------------------------------------------------------- host
static inline int cdiv(int a, int b) { return (a + b - 1) / b; }

extern "C" void kernel_launch(void* const* d_in, const int* in_sizes, int n_in,
                              void* d_out, int out_size, void* d_ws, size_t ws_size,
                              hipStream_t stream) {
  (void)n_in; (void)out_size; (void)ws_size;
  const float* feats  = (const float*)d_in[0];
  const int*   coords = (const int*)d_in[1];
  const float* w_mlp = (const float*)d_in[2];
  const float* gm  = (const float*)d_in[3];  const float* bm  = (const float*)d_in[4];
  const float* W1  = (const float*)d_in[5];  const float* g1  = (const float*)d_in[6];  const float* b1  = (const float*)d_in[7];
  const float* W2  = (const float*)d_in[8];  const float* g2  = (const float*)d_in[9];  const float* b2  = (const float*)d_in[10];
  const float* W3  = (const float*)d_in[11]; const float* g3  = (const float*)d_in[12]; const float* b3  = (const float*)d_in[13];
  const float* W4  = (const float*)d_in[14]; const float* g4  = (const float*)d_in[15]; const float* b4  = (const float*)d_in[16];
  const float* W5a = (const float*)d_in[17]; const float* g5a = (const float*)d_in[18]; const float* b5a = (const float*)d_in[19];
  const float* W5b = (const float*)d_in[20]; const float* g5b = (const float*)d_in[21]; const float* b5b = (const float*)d_in[22];
  const float* W5c = (const float*)d_in[23]; const float* g5c = (const float*)d_in[24]; const float* b5c = (const float*)d_in[25];
  const int*   lvl[7];
  for (int i = 0; i < 7; ++i) lvl[i] = (const int*)d_in[26 + i];

  const int N = in_sizes[0];
  int nl[7];
  for (int i = 0; i < 7; ++i) nl[i] = in_sizes[26 + i] / 4;
  const int n2 = nl[0], n4 = nl[1], n8 = nl[2], n16 = nl[3], n32 = nl[4], n64 = nl[5], n128 = nl[6];

  char* ws = (char*)d_ws;
  size_t off = 0;
  auto alloc = [&](size_t bytes) -> char* {
    off = (off + 255) & ~(size_t)255;
    char* p = ws + off;
    off += bytes;
    return p;
  };

  struct Tab { int* keys; int* vals; unsigned mask; int sh; int Gs; int n; const int* src; };
  Tab tab[8];
  const int* tsrc[8] = {coords, lvl[0], lvl[1], lvl[2], lvl[3], lvl[4], lvl[5], lvl[6]};
  int tn[8] = {N, n2, n4, n8, n16, n32, n64, n128};
  for (int i = 0; i < 8; ++i) {
    int cap = 64;
    while (cap < 2 * tn[i]) cap <<= 1;
    tab[i].keys = (int*)alloc((size_t)cap * 4);
    tab[i].vals = (int*)alloc((size_t)cap * 4);
    tab[i].mask = (unsigned)(cap - 1);
    tab[i].sh = i;
    tab[i].Gs = GDIM >> i;
    tab[i].n = tn[i];
    tab[i].src = tsrc[i];
  }

  int* pout   = (int*)alloc((size_t)27 * N * 4);   // owner lists
  int* pin    = (int*)alloc((size_t)27 * N * 4);
  int* pout_r = (int*)alloc((size_t)27 * N * 4);   // rest lists
  int* pin_r  = (int*)alloc((size_t)27 * N * 4);
  int* counts = (int*)alloc(256);                  // [0..26] owner, [27..53] rest
  int* plan   = (int*)alloc(256);                  // [0..27] owner bstart, [28..55] rest
  int* idxbuf = (int*)alloc((size_t)27 * N * 4);
  int* sidx[4];
  for (int i = 0; i < 4; ++i) sidx[i] = (int*)alloc((size_t)N * 4);
  float* bnsum = (float*)alloc(2 * 1024 * 4);
  float* abuf  = (float*)alloc(2 * 1024 * 4);

  auto mxz = [](size_t a, size_t b) { return a > b ? a : b; };
  size_t szA = mxz(mxz((size_t)N * 32, (size_t)n4 * 64), (size_t)n64 * 128) * 4;
  size_t szB = mxz(mxz((size_t)N * 48, (size_t)n16 * 96), (size_t)n2 * 256) * 4;
  float* RA = (float*)alloc(szA);
  float* RB = (float*)alloc(szB);
  float* RG = (float*)alloc((size_t)n4 * 512 * 4);                                 // t5b
  unsigned short* xb  = (unsigned short*)alloc((size_t)N * 32 * 2);
  unsigned short* y1b = (unsigned short*)alloc((size_t)n2 * 48 * 2);
  unsigned short* y2b = (unsigned short*)alloc((size_t)n8 * 64 * 2);
  unsigned short* y3b = (unsigned short*)alloc((size_t)n32 * 96 * 2);
  unsigned short* y4b = (unsigned short*)alloc((size_t)n128 * 128 * 2);
  unsigned short* xcb = (unsigned short*)alloc((size_t)N * 336 * 2);
  unsigned short* t5bb = (unsigned short*)alloc((size_t)n4 * 512 * 2);
  short* Wt1  = (short*)alloc((size_t)27 * 32 * 48 * 2);
  short* Wt2  = (short*)alloc((size_t)27 * 48 * 64 * 2);
  short* Wt3  = (short*)alloc((size_t)27 * 64 * 96 * 2);
  short* Wt4  = (short*)alloc((size_t)27 * 96 * 128 * 2);
  short* Wt5a = (short*)alloc((size_t)27 * 336 * 256 * 2);
  short* Wt5b = (short*)alloc((size_t)27 * 256 * 512 * 2);
  short* Wt5c = (short*)alloc((size_t)27 * 512 * 1024 * 2);

  // hash tables
  for (int i = 0; i < 8; ++i)
    hipMemsetAsync(tab[i].keys, 0xFF, (size_t)(tab[i].mask + 1) * 4, stream);
  for (int i = 0; i < 8; ++i)
    k_build_table<<<cdiv(tab[i].n, 256), 256, 0, stream>>>(
        tab[i].src, tab[i].n, tab[i].sh, tab[i].Gs, tab[i].keys, tab[i].vals, tab[i].mask);

  auto convW = [&](const float* W, short* Wt, int cin, int cout) {
    dim3 g(cdiv(cout, 32), cdiv(cin, 32), 27);
    k_convert_w<<<g, 256, 0, stream>>>(W, Wt, cin, cout);
  };
  convW(W1, Wt1, 32, 48);     convW(W2, Wt2, 48, 64);
  convW(W3, Wt3, 64, 96);     convW(W4, Wt4, 96, 128);
  convW(W5a, Wt5a, 336, 256); convW(W5b, Wt5b, 256, 512);
  convW(W5c, Wt5c, 512, 1024);

  auto conv = [&](const unsigned short* Fb, const short* Wt, const int* oc, int m,
                  const Tab& t, int cin, int cout, float* out) {
    hipMemsetAsync(counts, 0, 54 * 4, stream);
    dim3 gq(cdiv(m, 256), 27);
    k_query_idx_t<<<gq, 256, 0, stream>>>(oc, m, t.sh, t.Gs, t.keys, t.vals, t.mask, idxbuf);
    k_make_pairs<<<cdiv(m, 256), 256, 0, stream>>>(idxbuf, m, pout, pin, pout_r, pin_r,
                                                   counts, N);
    k_plan<<<1, 64, 0, stream>>>(counts, plan);
    int cin_pad = (cin + 31) & ~31;
    int nT = cdiv(cout, 128);
    int GY = cdiv(m, 128) + 27;
    if (GY > 2048) GY = 2048;
    dim3 gridc(nT, GY);  // x = cout tile (fast) -> A-tile L2 reuse
    k_conv_mfma<true><<<gridc, 256, 0, stream>>>(Fb, Wt, out, pout, pin, counts, plan,
                                                 cin, cin_pad, cout, N);
    k_conv_mfma<false><<<gridc, 256, 0, stream>>>(Fb, Wt, out, pout_r, pin_r, counts + 27,
                                                  plan + 28, cin, cin_pad, cout, N);
  };
  auto stats = [&](const float* x, int m, int C, const float* gamma, const float* beta) {
    hipMemsetAsync(bnsum, 0, (size_t)2 * C * 4, stream);
    int CG = (C >= 256) ? (C / 256) : 1;
    int RL = (C >= 256) ? 1 : (256 / C);
    int NS = (C >= 256) ? 512 : 256;
    int maxNS = cdiv(m, RL);
    if (NS > maxNS) NS = maxNS < 1 ? 1 : maxNS;
    dim3 g(NS, CG);
    k_bn_stats<<<g, 256, 0, stream>>>(x, m, C, bnsum);
    k_bn_finalize<<<1, 256, 0, stream>>>(bnsum, gamma, beta, C, 1.0f / (float)m, abuf);
  };
  auto pool = [&](const float* F, const int* oc, int m, const Tab& t, int C,
                  unsigned short* out) {
    k_query_idx<<<cdiv(m * 27, 256), 256, 0, stream>>>(
        oc, m, t.sh, t.Gs, t.keys, t.vals, t.mask, idxbuf);
    long long total = (long long)m * C;
    k_maxpool_bn<<<(int)((total + 255) / 256), 256, 0, stream>>>(F, out, idxbuf, m, C, abuf);
  };
  auto cvt = [&](const float* src, unsigned short* dst, long long total, int C) {
    long long t4 = total / 4;
    k_bn_bf16<<<(int)((t4 + 255) / 256), 256, 0, stream>>>(src, dst, t4, C, abuf);
  };

  // ---- network ----
  float* x = RA;
  k_mlp<<<cdiv(N * 32, 256), 256, 0, stream>>>(feats, w_mlp, x, N);
  stats(x, N, 32, gm, bm);
  cvt(x, xb, (long long)N * 32, 32);                    // bn(mlp)+lrelu -> bf16

  float* t1 = RB;
  conv(xb, Wt1, coords, N, tab[0], 32, 48, t1);
  stats(t1, N, 48, g1, b1);
  pool(t1, lvl[0], n2, tab[0], 48, y1b);

  float* t2 = RA;
  conv(y1b, Wt2, lvl[1], n4, tab[1], 48, 64, t2);
  stats(t2, n4, 64, g2, b2);
  pool(t2, lvl[2], n8, tab[2], 64, y2b);

  float* t3 = RB;
  conv(y2b, Wt3, lvl[3], n16, tab[3], 64, 96, t3);
  stats(t3, n16, 96, g3, b3);
  pool(t3, lvl[4], n32, tab[4], 96, y3b);

  float* t4 = RA;
  conv(y3b, Wt4, lvl[5], n64, tab[5], 96, 128, t4);
  stats(t4, n64, 128, g4, b4);
  pool(t4, lvl[6], n128, tab[6], 128, y4b);

  // slice_to_field -> xcb (bf16)
  k_slice_idx<<<cdiv(N, 256), 256, 0, stream>>>(coords, N, tab[1].sh, tab[1].Gs,
                                                tab[1].keys, tab[1].vals, tab[1].mask, sidx[0]);
  k_slice_idx<<<cdiv(N, 256), 256, 0, stream>>>(coords, N, tab[3].sh, tab[3].Gs,
                                                tab[3].keys, tab[3].vals, tab[3].mask, sidx[1]);
  k_slice_idx<<<cdiv(N, 256), 256, 0, stream>>>(coords, N, tab[5].sh, tab[5].Gs,
                                                tab[5].keys, tab[5].vals, tab[5].mask, sidx[2]);
  k_slice_idx<<<cdiv(N, 256), 256, 0, stream>>>(coords, N, tab[7].sh, tab[7].Gs,
                                                tab[7].keys, tab[7].vals, tab[7].mask, sidx[3]);
  k_gather_cols16<<<(int)(((long long)N * 48 + 255) / 256), 256, 0, stream>>>(y1b, 48, sidx[0], xcb, 336, 0, N);
  k_gather_cols16<<<(int)(((long long)N * 64 + 255) / 256), 256, 0, stream>>>(y2b, 64, sidx[1], xcb, 336, 48, N);
  k_gather_cols16<<<(int)(((long long)N * 96 + 255) / 256), 256, 0, stream>>>(y3b, 96, sidx[2], xcb, 336, 112, N);
  k_gather_cols16<<<(int)(((long long)N * 128 + 255) / 256), 256, 0, stream>>>(y4b, 128, sidx[3], xcb, 336, 208, N);

  float* t5a = RB;
  conv(xcb, Wt5a, lvl[0], n2, tab[0], 336, 256, t5a);
  stats(t5a, n2, 256, g5a, b5a);
  unsigned short* t5ab = xcb;  // xcb free after conv5a
  cvt(t5a, t5ab, (long long)n2 * 256, 256);

  float* t5b = RG;
  conv(t5ab, Wt5b, lvl[1], n4, tab[1], 256, 512, t5b);
  stats(t5b, n4, 512, g5b, b5b);
  cvt(t5b, t5bb, (long long)n4 * 512, 512);

  float* outp = (float*)d_out;
  conv(t5bb, Wt5c, lvl[2], n8, tab[2], 512, 1024, outp);
  stats(outp, n8, 1024, g5c, b5c);
  long long total4 = (long long)n8 * 1024 / 4;
  k_bn_apply<<<(int)((total4 + 255) / 256), 256, 0, stream>>>(outp, total4, 1024, abuf);
}